// Round 5
// baseline (3887.482 us; speedup 1.0000x reference)
//
#include <hip/hip_runtime.h>
#include <math.h>

// SparseCoding, round 18.
// R17 post-mortem: 3977 us, VGPR_Count=64 -> ~56 hot-spilled regs/thread.
// __launch_bounds__(1024,4)'s arg2 behaved as WORKGROUPS/CU on this compiler:
// 4 blk x 16 waves = 64 waves/CU, clamped to 32 = 8 waves/EU -> 64-VGPR cap.
// Empirical allocator record: (512,2)->128, (512,1)->128, (1024,4)->64.
// R18 = R17 with __launch_bounds__(1024,1): a 1024-thr block needs <=128 VGPR
// to schedule at all (4 waves/SIMD x VGPR <= 512/lane), so the cap is exactly
// the ~120-VGPR demand. Everything else byte-identical to R17:
//  * 1 block = 1 window; 16 waves x 16 N-cols; G frags 64 VGPR (hi/lo bf16);
//    A-stack 64x256 bf16 double-buffered, XOR-swizzled; 64 MFMA/wave/iter.
//  * Setup xB bit-identical to R13 chains; loss/lag-2/stop machinery LDS-local.
#define NB     256
#define NF     128
#define FT     1024
#define NW     63
#define TORIG  256
#define RPB    8
#define GRID   256

using f32x4  = __attribute__((ext_vector_type(4))) float;
using bf16x8 = __attribute__((ext_vector_type(8))) short;

// setup xB exchange layout (float4 index): k2*512 + row*64 + (cg ^ row)
__device__ __forceinline__ int xidx(int k2, int cg, int row) {
    return (k2 * 512 + row * 64 + (cg ^ row)) * 4;
}

// round-to-nearest-even fp32 -> bf16 bits (upper 16)
__device__ __forceinline__ unsigned bf16_hi(float x) {
    const unsigned u = __float_as_uint(x);
    return (u + 0x7fffu + ((u >> 16) & 1u)) >> 16;
}

__global__ __launch_bounds__(1024, 1) void window_kernel(
    const float* __restrict__ spec,
    const float* __restrict__ basis,
    float* __restrict__ G,               // ws: 256x256
    const int* __restrict__ p_niter,
    const int* __restrict__ p_pad,
    const int* __restrict__ p_stride,
    unsigned int* __restrict__ gbar,     // single word, memset 0
    float* __restrict__ out)             // (32,256,63)
{
    // arena: setup = s_p0 (64KB xB exchange); loop = A0 @0 / A1 @32768 (bytes)
    __shared__ __align__(16) char arena[65536];
    float* const s_p0 = (float*)arena;
    __shared__ __align__(16) float s_xn[RPB * FT];   // 32KB staging (per group)
    __shared__ float  s_gred[4][NB];
    __shared__ float  s_mn[RPB], s_rng[RPB];
    __shared__ double s_dred[16];
    __shared__ double s_sx;
    __shared__ float  s_redq[2][16], s_redr[2][16];
    __shared__ int    s_stop[2];

    const int bid = blockIdx.x;
    const int tid = threadIdx.x;
    const int ks  = tid >> 6;                    // wave 0..15
    const int kg  = tid & 63;
    const int lr  = kg & 15;                     // C col within 16-tile
    const int lh  = kg >> 4;                     // lane group 0..3
    const int n_iter = p_niter[0];

    // ================= fused Gram: block bid computes G row bid ==================
    {
        const int c = tid & 255, jh = tid >> 8;  // 4 j-quarters
        float acc = 0.f;
        const float* bp = basis + (size_t)(jh * 256) * NB;
        #pragma unroll 16
        for (int j = 0; j < 256; ++j)
            acc = fmaf(bp[j * NB + bid], bp[j * NB + c], acc);
        s_gred[jh][c] = acc;
        __syncthreads();
        if (jh == 0)
            G[(size_t)bid * NB + c] =
                s_gred[0][c] + s_gred[1][c] + s_gred[2][c] + s_gred[3][c];
    }
    __threadfence();
    __syncthreads();
    if (tid == 0) atomicAdd(gbar, 1u);
    if (bid >= NW) return;                       // 193 blocks exit after Gram

    const int w  = bid;
    const int t0 = w * p_stride[0] - p_pad[0];
    if (tid == 0) s_sx = 0.0;

    const int cc = 16 * ks + lr;                 // owned column (loop phase)
    float xB[8];

    // ======== setup per 8-row group: stage, normalize, xB (R13 arithmetic) ======
    #pragma unroll 1
    for (int rg = 0; rg < 4; ++rg) {
        #pragma unroll
        for (int i = 0; i < 8; ++i) {
            const int e = i * 1024 + tid;
            const int b = e >> 10, jj = e & 1023;
            const int f = jj >> 3, t = jj & 7, tq = t0 + t;
            s_xn[b * FT + jj] = (tq >= 0 && tq < TORIG)
                ? spec[((size_t)(rg * RPB + b) * NF + f) * TORIG + tq] : 0.f;
        }
        __syncthreads();
        if (ks < 8) {   // wave ks scans row ks
            float mn = __builtin_inff(), mx = -__builtin_inff();
            #pragma unroll
            for (int i = 0; i < 16; ++i) {
                const float v = s_xn[ks * FT + i * 64 + kg];
                mn = fminf(mn, v); mx = fmaxf(mx, v);
            }
            #pragma unroll
            for (int off = 32; off; off >>= 1) {
                mn = fminf(mn, __shfl_down(mn, off));
                mx = fmaxf(mx, __shfl_down(mx, off));
            }
            if (kg == 0) { s_mn[ks] = mn; s_rng[ks] = mx - mn; }
        }
        __syncthreads();
        double sx2p = 0.0;
        #pragma unroll
        for (int i = 0; i < 8; ++i) {
            const int e = i * 1024 + tid;
            const int b = e >> 10, jj = e & 1023;
            const float v = (s_xn[b * FT + jj] - s_mn[b]) / s_rng[b];
            s_xn[b * FT + jj] = v;
            sx2p += (double)v * (double)v;
        }
        #pragma unroll
        for (int off = 32; off; off >>= 1) sx2p += __shfl_down(sx2p, off);
        if (kg == 0) s_dred[ks] = sx2p;
        __syncthreads();
        if (tid == 0) {
            double s = 0.0;
            #pragma unroll
            for (int i = 0; i < 16; ++i) s += s_dred[i];
            s_sx += s;
        }

        // xB partials: wave pair (2u, 2u+1) = K-slice u, rows 4*(ks&1)..+4.
        // Per-row fma chains are bit-identical to R13's wave-u chains.
        const int u = ks >> 1, hf2 = ks & 1;
        float xbp[4][4];
        #pragma unroll
        for (int b = 0; b < 4; ++b)
            #pragma unroll
            for (int j = 0; j < 4; ++j) xbp[b][j] = 0.f;
        for (int i0 = 0; i0 < 128; i0 += 4) {
            const int jj = u * 128 + i0;
            float4 bv[4];
            #pragma unroll
            for (int t = 0; t < 4; ++t)
                bv[t] = *(const float4*)(basis + (size_t)(jj + t) * NB + 4 * kg);
            #pragma unroll
            for (int b = 0; b < 4; ++b) {
                const float4 x4 = *(const float4*)&s_xn[(4 * hf2 + b) * FT + jj];
                xbp[b][0] = fmaf(x4.x, bv[0].x, fmaf(x4.y, bv[1].x, fmaf(x4.z, bv[2].x, fmaf(x4.w, bv[3].x, xbp[b][0]))));
                xbp[b][1] = fmaf(x4.x, bv[0].y, fmaf(x4.y, bv[1].y, fmaf(x4.z, bv[2].y, fmaf(x4.w, bv[3].y, xbp[b][1]))));
                xbp[b][2] = fmaf(x4.x, bv[0].z, fmaf(x4.y, bv[1].z, fmaf(x4.z, bv[2].z, fmaf(x4.w, bv[3].z, xbp[b][2]))));
                xbp[b][3] = fmaf(x4.x, bv[0].w, fmaf(x4.y, bv[1].w, fmaf(x4.z, bv[2].w, fmaf(x4.w, bv[3].w, xbp[b][3]))));
            }
        }
        #pragma unroll
        for (int b = 0; b < 4; ++b)
            *(float4*)&s_p0[xidx(u, kg, 4 * hf2 + b)] =
                make_float4(xbp[b][0], xbp[b][1], xbp[b][2], xbp[b][3]);
        __syncthreads();
        // gather owned coefs whose rows fall in this group (ascending u = R13
        // order); static destination index via rg<2 branch.
        if ((lh >> 1) == (rg & 1)) {
            float vv[4];
            #pragma unroll
            for (int t = 0; t < 4; ++t) {
                const int r8 = 4 * (lh & 1) + t;
                float s = 0.f;
                #pragma unroll
                for (int u2 = 0; u2 < 8; ++u2)
                    s += s_p0[xidx(u2, cc >> 2, r8) + (cc & 3)];
                vv[t] = s;
            }
            if (rg < 2) { xB[0] = vv[0]; xB[1] = vv[1]; xB[2] = vv[2]; xB[3] = vv[3]; }
            else        { xB[4] = vv[0]; xB[5] = vv[1]; xB[6] = vv[2]; xB[7] = vv[3]; }
        }
    }

    // ================= wait for G; init block-local state ========================
    if (tid == 0) {
        while (__hip_atomic_load(gbar, __ATOMIC_ACQUIRE, __HIP_MEMORY_SCOPE_AGENT) < (unsigned)GRID)
            __builtin_amdgcn_s_sleep(1);
    }
    if (tid == 64) { s_stop[0] = 0; s_stop[1] = 0; }
    __syncthreads();   // all gathers done -> arena reusable as A0/A1

    // G B-fragments (wave's 16 cols, full K), hi/lo bf16 split.
    // B layout: col = lane&15, k = 8*(lane>>4) + b + 32*kk.
    bf16x8 Gh[8], Gl[8];
    {
        const float* gp = G + (size_t)(8 * lh) * NB + cc;
        #pragma unroll
        for (int kk = 0; kk < 8; ++kk)
            #pragma unroll
            for (int b = 0; b < 8; ++b) {
                const float gv = gp[(size_t)(32 * kk + b) * NB];
                const unsigned hb = bf16_hi(gv);
                const float    hf = __uint_as_float(hb << 16);
                Gh[kk][b] = (short)hb;
                Gl[kk][b] = (short)bf16_hi(gv - hf);
            }
    }

    // A tile: 64x256 bf16 (rows 0-31 hi, 32-63 lo); swizzle short-idx ^= (row&7)<<3.
    const int ro  = lr * 256 + 8 * lh;           // read base (shorts), Mtile 0
    const int swz = (lr & 7) << 3;

    // ================= init owned coef / Adam; write A0 ==========================
    const float C0 = 0.5f / 256.f;
    float cf[8], m_[8], v_[8];
    #pragma unroll
    for (int j = 0; j < 8; ++j) { cf[j] = C0; m_[j] = 0.f; v_[j] = 0.f; }
    {
        const short vh = (short)bf16_hi(C0);     // C0 = 2^-9 exact, lo = 0
        #pragma unroll
        for (int pp = 0; pp < 2; ++pp)
            #pragma unroll
            for (int t = 0; t < 4; ++t) {
                const int rr = 16 * pp + 4 * lh + t;
                const int wb = ((rr * 256 + cc) ^ ((rr & 7) << 3)) << 1;
                *(short*)(arena + wb)         = vh;   // hi row
                *(short*)(arena + wb + 16384) = 0;    // lo row (+32 rows)
            }
    }
    float b1p = 1.f, b2p = 1.f;
    float old_loss = 1e-10f;      // tid64 only
    double sxtot = 0.0;           // tid64 only
    const float c1c = 2.f / 32768.f, c2c = 0.2f / 8192.f;
    int use_prev = 0;

    for (int it = 0; it < n_iter; ++it) {
        const int p = it & 1;
        const char* rdb = arena + (p ? 32768 : 0);
        char*       wrb = arena + (p ? 0 : 32768);

        __syncthreads();          // barrier 1: A[rdb] writes (prev iter) visible

        // ---- MFMA: (Ahi+Alo) @ (Ghi+Glo); acc0 = coef rows 0-15, acc1 = 16-31 ----
        f32x4 acc0 = {0.f, 0.f, 0.f, 0.f}, acc1 = {0.f, 0.f, 0.f, 0.f};
        #pragma unroll 2
        for (int kk = 0; kk < 8; ++kk) {
            const int o = ro + 32 * kk;
            const bf16x8 ah0 = *(const bf16x8*)(rdb + (((o        ) ^ swz) << 1));
            const bf16x8 ah1 = *(const bf16x8*)(rdb + (((o +  4096) ^ swz) << 1));
            const bf16x8 al0 = *(const bf16x8*)(rdb + (((o +  8192) ^ swz) << 1));
            const bf16x8 al1 = *(const bf16x8*)(rdb + (((o + 12288) ^ swz) << 1));
            acc0 = __builtin_amdgcn_mfma_f32_16x16x32_bf16(ah0, Gh[kk], acc0, 0, 0, 0);
            acc0 = __builtin_amdgcn_mfma_f32_16x16x32_bf16(al0, Gh[kk], acc0, 0, 0, 0);
            acc0 = __builtin_amdgcn_mfma_f32_16x16x32_bf16(ah0, Gl[kk], acc0, 0, 0, 0);
            acc0 = __builtin_amdgcn_mfma_f32_16x16x32_bf16(al0, Gl[kk], acc0, 0, 0, 0);
            acc1 = __builtin_amdgcn_mfma_f32_16x16x32_bf16(ah1, Gh[kk], acc1, 0, 0, 0);
            acc1 = __builtin_amdgcn_mfma_f32_16x16x32_bf16(al1, Gh[kk], acc1, 0, 0, 0);
            acc1 = __builtin_amdgcn_mfma_f32_16x16x32_bf16(ah1, Gl[kk], acc1, 0, 0, 0);
            acc1 = __builtin_amdgcn_mfma_f32_16x16x32_bf16(al1, Gl[kk], acc1, 0, 0, 0);
        }

        // ---- tid64: LAG-2 consume, LDS-local (parity ring = lag-2 store) ----
        if (tid == 64 && it >= 2) {
            const int itc = it - 2;
            double Qt = 0.0, Rt = 0.0;
            #pragma unroll
            for (int i = 0; i < 16; ++i) {
                Qt += (double)s_redq[p][i];
                Rt += (double)s_redr[p][i];
            }
            if (itc == 0) sxtot = s_sx;
            const float loss = (float)((Qt + sxtot) / 32768.0 + 0.2 * (Rt / 8192.0));
            const float stat = fabsf(old_loss - loss) / old_loss;
            old_loss = loss;
            s_stop[p] = (stat < 1e-3f) ? 1 : 0;
        }

        __syncthreads();          // barrier 2: s_stop[p] + ring consume done

        if (s_stop[p]) { use_prev = 1; break; }

        // ---- loss partials -> parity ring (block-local) ----
        if (it + 1 < n_iter) {
            float qc = 0.f, rr_ = 0.f;
            #pragma unroll
            for (int j = 0; j < 8; ++j) {
                const float a4v = (j < 4) ? acc0[j] : acc1[j - 4];
                qc += cf[j] * (a4v - 2.f * xB[j]);
                rr_ += fabsf(cf[j]);
            }
            #pragma unroll
            for (int off = 32; off; off >>= 1) {
                qc  += __shfl_down(qc, off);
                rr_ += __shfl_down(rr_, off);
            }
            if (kg == 0) { s_redq[p][ks] = qc; s_redr[p][ks] = rr_; }
        }

        // ---- Adam update (fast rcp/sqrt) ----
        b1p *= 0.9f; b2p *= 0.999f;
        const float rb1 = __builtin_amdgcn_rcpf(1.f - b1p);
        const float rb2 = __builtin_amdgcn_rcpf(1.f - b2p);
        #pragma unroll
        for (int j = 0; j < 8; ++j) {
            const float a4v = (j < 4) ? acc0[j] : acc1[j - 4];
            const float c_  = cf[j];
            const float sgn = (c_ > 0.f) ? 1.f : ((c_ < 0.f) ? -1.f : 0.f);
            const float gg  = c1c * (a4v - xB[j]) + c2c * sgn;
            m_[j] = 0.9f * m_[j] + 0.1f * gg;
            v_[j] = 0.999f * v_[j] + 0.001f * gg * gg;
            const float den = __builtin_amdgcn_sqrtf(v_[j] * rb2) + 1e-8f;
            cf[j] = c_ - 1e-3f * (m_[j] * rb1) * __builtin_amdgcn_rcpf(den);
        }

        // ---- bf16 hi/lo split of new coef -> next A buffer ----
        #pragma unroll
        for (int pp = 0; pp < 2; ++pp)
            #pragma unroll
            for (int t = 0; t < 4; ++t) {
                const int j  = pp * 4 + t;
                const int rr = 16 * pp + 4 * lh + t;
                const int wb = ((rr * 256 + cc) ^ ((rr & 7) << 3)) << 1;
                const unsigned hb = bf16_hi(cf[j]);
                const float    hf = __uint_as_float(hb << 16);
                *(short*)(wrb + wb)         = (short)hb;
                *(short*)(wrb + wb + 16384) = (short)bf16_hi(cf[j] - hf);
            }
    }

    // ---- post-loop consume round: conv at t = n_iter-2 (if not already stopped) ----
    if (!use_prev && n_iter >= 2) {
        if (tid == 64) {
            const int itc = n_iter - 2;
            const int pc  = itc & 1;
            double Qt = 0.0, Rt = 0.0;
            #pragma unroll
            for (int i = 0; i < 16; ++i) {
                Qt += (double)s_redq[pc][i];
                Rt += (double)s_redr[pc][i];
            }
            if (itc == 0) sxtot = s_sx;
            const float loss = (float)((Qt + sxtot) / 32768.0 + 0.2 * (Rt / 8192.0));
            const float stat = fabsf(old_loss - loss) / old_loss;
            s_stop[0] = (stat < 1e-3f) ? 1 : 0;
        }
        __syncthreads();
        use_prev = s_stop[0];
    }

    // ---- output; on stop reconstruct pre-step coef by exact Adam-step undo ----
    {
        const float rb1e = __builtin_amdgcn_rcpf(1.f - b1p);
        const float rb2e = __builtin_amdgcn_rcpf(1.f - b2p);
        #pragma unroll
        for (int pp = 0; pp < 2; ++pp)
            #pragma unroll
            for (int t = 0; t < 4; ++t) {
                const int j = pp * 4 + t;
                float val = cf[j];
                if (use_prev) {
                    const float den = __builtin_amdgcn_sqrtf(v_[j] * rb2e) + 1e-8f;
                    val += 1e-3f * (m_[j] * rb1e) * __builtin_amdgcn_rcpf(den);
                }
                out[((size_t)(16 * pp + 4 * lh + t) * NB + cc) * NW + w] = val;
            }
    }
}

// ---------------------------------------------------------------------------
extern "C" void kernel_launch(void* const* d_in, const int* in_sizes, int n_in,
                              void* d_out, int out_size, void* d_ws, size_t ws_size,
                              hipStream_t stream)
{
    const float* spec   = (const float*)d_in[0];
    const float* basis  = (const float*)d_in[1];
    const int* p_niter  = (const int*)d_in[2];
    const int* p_pad    = (const int*)d_in[3];
    const int* p_stride = (const int*)d_in[4];
    float* out = (float*)d_out;

    char* ws = (char*)d_ws;
    float*        G    = (float*)ws;                 // 256 KB
    unsigned int* gbar = (unsigned int*)(ws + 262144);

    hipMemsetAsync(gbar, 0, sizeof(unsigned int), stream);
    window_kernel<<<dim3(GRID), dim3(1024), 0, stream>>>(
        spec, basis, G, p_niter, p_pad, p_stride, gbar, out);
}

// Round 6
// 514.443 us; speedup vs baseline: 7.5567x; 7.5567x over previous
//
#include <hip/hip_runtime.h>
#include <math.h>

// SparseCoding, round 19.
// R17/R18 verdict: 1024-thr blocks are capped at 64 arch VGPRs by this
// toolchain (record: (512,2)->128, (512,1)->128, (1024,*)->64) -> hot spills.
// R19 returns to 512-thr blocks (proven 128) and removes the >128 demand:
//  * G NEVER lives in registers: bf16 hi/lo PLANES of G precomputed in the
//    Gram phase (G symmetric -> row-writes produce the col-major layout the
//    B-fragment needs: 8 contiguous k-shorts, 16B aligned). The loop streams
//    Gh/Gl from L2 per K-step (32KB/wave/iter; 484MB aggregate ~ 14us of L2).
//  * Setup is 252-block parallel (R13's 4-blocks/window, 8 rows each,
//    bit-identical xB chains); one-time transport: xB rides through `out`
//    as scratch (write-only until epilogue, layout matches), sx via small
//    ws array + per-window arrival counter. NO per-iteration global traffic.
//  * Loop: 63 blocks, 8 waves, C=32/wave. A-stack 64x256 bf16 (hi rows 0-31,
//    lo 32-63) double-buffered + XOR swizzle; 12 MFMA/kk (lo*lo pruned,
//    <=2^-18 rel). xB in LDS (16 ds_read_b32/iter) to hold demand ~120.
//  * Stop machinery = R18 verbatim (LDS parity ring width 8, tid64 lag-2
//    consume, post-loop round, Adam-undo epilogue).
#define NB     256
#define NF     128
#define FT     1024
#define NW     63
#define TORIG  256
#define RPB    8
#define GRID   256

using f32x4  = __attribute__((ext_vector_type(4))) float;
using bf16x8 = __attribute__((ext_vector_type(8))) short;

// setup xB exchange layout (float4 index): k2*512 + row*64 + (cg ^ row)
__device__ __forceinline__ int xidx(int k2, int cg, int row) {
    return (k2 * 512 + row * 64 + (cg ^ row)) * 4;
}

// round-to-nearest-even fp32 -> bf16 bits (upper 16)
__device__ __forceinline__ unsigned bf16_hi(float x) {
    const unsigned u = __float_as_uint(x);
    return (u + 0x7fffu + ((u >> 16) & 1u)) >> 16;
}

__global__ __launch_bounds__(512, 1) void window_kernel(
    const float* __restrict__ spec,
    const float* __restrict__ basis,
    short* __restrict__ Ghi,             // ws: 256x256 bf16 hi plane
    short* __restrict__ Glo,             // ws: 256x256 bf16 lo plane
    const int* __restrict__ p_niter,
    const int* __restrict__ p_pad,
    const int* __restrict__ p_stride,
    double* __restrict__ sxw,            // ws: [NW][4] sx partials
    unsigned int* __restrict__ arr,      // ws: [NW] setup arrivals (memset 0)
    unsigned int* __restrict__ gbar,     // ws: single word (memset 0)
    float* __restrict__ out)             // (32,256,63); used as xB scratch too
{
    // arena: setup = s_p0 (64KB exchange); loop = A0 @0 / A1 @32768 (bytes)
    __shared__ __align__(16) char arena[65536];
    // s_xnb: setup = s_xn staging (8x1024 f32); loop = s_xb (32x256 f32)
    __shared__ __align__(16) float s_xnb[8192];
    __shared__ float  s_gred[2][NB];
    __shared__ float  s_mn[RPB], s_rng[RPB];
    __shared__ double s_dred[8];
    __shared__ float  s_redq[2][8], s_redr[2][8];
    __shared__ int    s_stop[2];

    const int bid = blockIdx.x;
    const int tid = threadIdx.x;
    const int ks  = tid >> 6;                    // wave 0..7
    const int kg  = tid & 63;
    const int yy  = bid >> 3;
    const int q   = yy & 3;
    const int w   = (bid & 7) + 8 * (yy >> 2);   // 4 blocks/window share bid%8
    const int n_iter = p_niter[0];

    // ================= fused Gram: block bid -> G row bid -> planes ==============
    {
        const int c = tid & 255, jh = tid >> 8;
        float acc = 0.f;
        const float* bp = basis + (size_t)(jh * 512) * NB;
        #pragma unroll 16
        for (int j = 0; j < 512; ++j)
            acc = fmaf(bp[j * NB + bid], bp[j * NB + c], acc);
        s_gred[jh][c] = acc;
        __syncthreads();
        if (jh == 0) {
            const float g = s_gred[0][c] + s_gred[1][c];
            const unsigned hb = bf16_hi(g);
            const float    hf = __uint_as_float(hb << 16);
            Ghi[(size_t)bid * NB + c] = (short)hb;            // plane[p][q]=G[p][q]
            Glo[(size_t)bid * NB + c] = (short)bf16_hi(g - hf);
        }
    }
    __threadfence();
    __syncthreads();
    if (tid == 0) atomicAdd(gbar, 1u);
    if (w >= NW) return;                         // 4 blocks exit after Gram

    const int t0 = w * p_stride[0] - p_pad[0];
    float* const s_p0 = (float*)arena;
    float* const s_xn = s_xnb;
    const int r   = kg >> 3;                     // setup owned row (of 8)
    const int cgo = 8 * ks + (kg & 7);           // setup owned colgroup

    // ========== setup (R13 verbatim): rows q*8..q*8+8 of window w ===============
    #pragma unroll
    for (int i = 0; i < 16; ++i) {
        const int e = i * 512 + tid;
        const int b = e >> 10, jj = e & 1023;
        const int f = jj >> 3, t = jj & 7, tq = t0 + t;
        s_xn[b * FT + jj] = (tq >= 0 && tq < TORIG)
            ? spec[((size_t)(q * RPB + b) * NF + f) * TORIG + tq] : 0.f;
    }
    __syncthreads();
    {   // wave ks scans row ks
        float mn = __builtin_inff(), mx = -__builtin_inff();
        #pragma unroll
        for (int i = 0; i < 16; ++i) {
            const float v = s_xn[ks * FT + i * 64 + kg];
            mn = fminf(mn, v); mx = fmaxf(mx, v);
        }
        #pragma unroll
        for (int off = 32; off; off >>= 1) {
            mn = fminf(mn, __shfl_down(mn, off));
            mx = fmaxf(mx, __shfl_down(mx, off));
        }
        if (kg == 0) { s_mn[ks] = mn; s_rng[ks] = mx - mn; }
    }
    __syncthreads();
    double sx2p = 0.0;
    #pragma unroll
    for (int i = 0; i < 16; ++i) {
        const int e = i * 512 + tid;
        const int b = e >> 10, jj = e & 1023;
        const float v = (s_xn[b * FT + jj] - s_mn[b]) / s_rng[b];
        s_xn[b * FT + jj] = v;
        sx2p += (double)v * (double)v;
    }
    #pragma unroll
    for (int off = 32; off; off >>= 1) sx2p += __shfl_down(sx2p, off);
    if (kg == 0) s_dred[ks] = sx2p;
    __syncthreads();
    if (tid == 0) {
        double s = 0.0;
        #pragma unroll
        for (int i = 0; i < 8; ++i) s += s_dred[i];
        sxw[w * 4 + q] = s;
    }

    // xB = xnorm @ basis, K-split partials (bit-identical R13 arithmetic)
    {
        float xbp[RPB][4];
        #pragma unroll
        for (int b = 0; b < RPB; ++b)
            #pragma unroll
            for (int j = 0; j < 4; ++j) xbp[b][j] = 0.f;
        for (int i0 = 0; i0 < 128; i0 += 4) {
            const int jj = ks * 128 + i0;
            float4 bv[4];
            #pragma unroll
            for (int t = 0; t < 4; ++t)
                bv[t] = *(const float4*)(basis + (size_t)(jj + t) * NB + 4 * kg);
            #pragma unroll
            for (int b = 0; b < RPB; ++b) {
                const float4 x4 = *(const float4*)&s_xn[b * FT + jj];
                xbp[b][0] = fmaf(x4.x, bv[0].x, fmaf(x4.y, bv[1].x, fmaf(x4.z, bv[2].x, fmaf(x4.w, bv[3].x, xbp[b][0]))));
                xbp[b][1] = fmaf(x4.x, bv[0].y, fmaf(x4.y, bv[1].y, fmaf(x4.z, bv[2].y, fmaf(x4.w, bv[3].y, xbp[b][1]))));
                xbp[b][2] = fmaf(x4.x, bv[0].z, fmaf(x4.y, bv[1].z, fmaf(x4.z, bv[2].z, fmaf(x4.w, bv[3].z, xbp[b][2]))));
                xbp[b][3] = fmaf(x4.x, bv[0].w, fmaf(x4.y, bv[1].w, fmaf(x4.z, bv[2].w, fmaf(x4.w, bv[3].w, xbp[b][3]))));
            }
        }
        __syncthreads();
        #pragma unroll
        for (int b = 0; b < RPB; ++b)
            *(float4*)&s_p0[xidx(ks, kg, b)] =
                make_float4(xbp[b][0], xbp[b][1], xbp[b][2], xbp[b][3]);
        __syncthreads();
        float xBo[4] = {0.f, 0.f, 0.f, 0.f};
        #pragma unroll
        for (int k2 = 0; k2 < 8; ++k2) {
            const float4 p4 = *(const float4*)&s_p0[xidx(k2, cgo, r)];
            xBo[0] += p4.x; xBo[1] += p4.y; xBo[2] += p4.z; xBo[3] += p4.w;
        }
        // one-time transport: xB rides in `out` (write-only until epilogue)
        #pragma unroll
        for (int j = 0; j < 4; ++j)
            out[((size_t)(q * RPB + r) * NB + 4 * cgo + j) * NW + w] = xBo[j];
    }
    __threadfence();
    __syncthreads();
    if (tid == 0)
        __hip_atomic_fetch_add(&arr[w], 1u, __ATOMIC_RELEASE, __HIP_MEMORY_SCOPE_AGENT);
    if (q != 0) return;                          // 189 blocks exit; 63 loop on

    // ================= loop block: wait siblings + Gram ==========================
    if (tid == 0) {
        while (__hip_atomic_load(&arr[w], __ATOMIC_ACQUIRE, __HIP_MEMORY_SCOPE_AGENT) < 4u)
            __builtin_amdgcn_s_sleep(1);
        while (__hip_atomic_load(gbar, __ATOMIC_ACQUIRE, __HIP_MEMORY_SCOPE_AGENT) < (unsigned)GRID)
            __builtin_amdgcn_s_sleep(1);
    }
    if (tid == 64) { s_stop[0] = 0; s_stop[1] = 0; }
    __syncthreads();   // arena + s_xnb reusable; remote data visible

    // s_xb fill (32x256) from out-scratch
    float* const s_xb = s_xnb;
    for (int i = tid; i < 32 * NB; i += 512)
        s_xb[i] = out[(size_t)i * NW + w];

    // ============== MFMA ownership (C=32/wave) & A0 init =========================
    const int lr  = kg & 15;                     // C col within 16-tile
    const int lh  = kg >> 4;                     // lane group -> C rows 4lh..4lh+3
    const int c0  = 32 * ks + lr;                // T0 col; T1 = c0+16
    const int roA = lr * NB + 8 * lh;            // A read base (shorts)
    const int swzA = (lr & 7) << 3;
    const short* ghp = Ghi + (size_t)c0 * NB + 8 * lh;   // +32kk ; +4096 for T1
    const short* glp = Glo + (size_t)c0 * NB + 8 * lh;

    const float C0 = 0.5f / 256.f;
    float cf[16], m_[16], v_[16];
    #pragma unroll
    for (int j = 0; j < 16; ++j) { cf[j] = C0; m_[j] = 0.f; v_[j] = 0.f; }
    {
        const short vh = (short)bf16_hi(C0);     // C0 = 2^-9 exact, lo = 0
        #pragma unroll
        for (int pp = 0; pp < 2; ++pp)
            #pragma unroll
            for (int T = 0; T < 2; ++T)
                #pragma unroll
                for (int t = 0; t < 4; ++t) {
                    const int arow = 16 * pp + 4 * lh + t;
                    const int col  = 32 * ks + 16 * T + lr;
                    const int wb = ((arow * NB + col) ^ ((arow & 7) << 3)) << 1;
                    *(short*)(arena + wb)         = vh;   // hi rows 0-31
                    *(short*)(arena + wb + 16384) = 0;    // lo rows 32-63
                }
    }
    float b1p = 1.f, b2p = 1.f;
    float old_loss = 1e-10f;      // tid64 only
    double sxtot = 0.0;           // tid64 only
    const float c1c = 2.f / 32768.f, c2c = 0.2f / 8192.f;
    int use_prev = 0;

    for (int it = 0; it < n_iter; ++it) {
        const int p = it & 1;
        const char* rdb = arena + (p ? 32768 : 0);
        char*       wrb = arena + (p ? 0 : 32768);

        __syncthreads();          // barrier 1: A[rdb] writes (prev iter) visible

        // ---- MFMA: (Ahi+Alo)@(Ghi+Glo), G streamed from L2, lo*lo pruned ----
        f32x4 acc00 = {0.f,0.f,0.f,0.f}, acc01 = {0.f,0.f,0.f,0.f};
        f32x4 acc10 = {0.f,0.f,0.f,0.f}, acc11 = {0.f,0.f,0.f,0.f};
        #pragma unroll 1
        for (int kk = 0; kk < 8; ++kk) {
            const int go = 32 * kk;
            const bf16x8 Gh0 = *(const bf16x8*)(ghp + go);
            const bf16x8 Gh1 = *(const bf16x8*)(ghp + 4096 + go);
            const bf16x8 Gl0 = *(const bf16x8*)(glp + go);
            const bf16x8 Gl1 = *(const bf16x8*)(glp + 4096 + go);
            const int o = roA + go;
            const bf16x8 ah0 = *(const bf16x8*)(rdb + (((o        ) ^ swzA) << 1));
            const bf16x8 ah1 = *(const bf16x8*)(rdb + (((o +  4096) ^ swzA) << 1));
            const bf16x8 al0 = *(const bf16x8*)(rdb + (((o +  8192) ^ swzA) << 1));
            const bf16x8 al1 = *(const bf16x8*)(rdb + (((o + 12288) ^ swzA) << 1));
            acc00 = __builtin_amdgcn_mfma_f32_16x16x32_bf16(ah0, Gh0, acc00, 0, 0, 0);
            acc00 = __builtin_amdgcn_mfma_f32_16x16x32_bf16(al0, Gh0, acc00, 0, 0, 0);
            acc00 = __builtin_amdgcn_mfma_f32_16x16x32_bf16(ah0, Gl0, acc00, 0, 0, 0);
            acc10 = __builtin_amdgcn_mfma_f32_16x16x32_bf16(ah1, Gh0, acc10, 0, 0, 0);
            acc10 = __builtin_amdgcn_mfma_f32_16x16x32_bf16(al1, Gh0, acc10, 0, 0, 0);
            acc10 = __builtin_amdgcn_mfma_f32_16x16x32_bf16(ah1, Gl0, acc10, 0, 0, 0);
            acc01 = __builtin_amdgcn_mfma_f32_16x16x32_bf16(ah0, Gh1, acc01, 0, 0, 0);
            acc01 = __builtin_amdgcn_mfma_f32_16x16x32_bf16(al0, Gh1, acc01, 0, 0, 0);
            acc01 = __builtin_amdgcn_mfma_f32_16x16x32_bf16(ah0, Gl1, acc01, 0, 0, 0);
            acc11 = __builtin_amdgcn_mfma_f32_16x16x32_bf16(ah1, Gh1, acc11, 0, 0, 0);
            acc11 = __builtin_amdgcn_mfma_f32_16x16x32_bf16(al1, Gh1, acc11, 0, 0, 0);
            acc11 = __builtin_amdgcn_mfma_f32_16x16x32_bf16(ah1, Gl1, acc11, 0, 0, 0);
        }

        // ---- tid64: LAG-2 consume, LDS-local (parity ring = lag-2 store) ----
        if (tid == 64 && it >= 2) {
            const int itc = it - 2;
            double Qt = 0.0, Rt = 0.0;
            #pragma unroll
            for (int i = 0; i < 8; ++i) {
                Qt += (double)s_redq[p][i];
                Rt += (double)s_redr[p][i];
            }
            if (itc == 0)
                sxtot = sxw[w*4+0] + sxw[w*4+1] + sxw[w*4+2] + sxw[w*4+3];
            const float loss = (float)((Qt + sxtot) / 32768.0 + 0.2 * (Rt / 8192.0));
            const float stat = fabsf(old_loss - loss) / old_loss;
            old_loss = loss;
            s_stop[p] = (stat < 1e-3f) ? 1 : 0;
        }

        __syncthreads();          // barrier 2: s_stop[p] + ring consume done

        if (s_stop[p]) { use_prev = 1; break; }

        // ---- fused loss-partial + Adam + A-write (cf read before update) ----
        b1p *= 0.9f; b2p *= 0.999f;
        const float rb1 = __builtin_amdgcn_rcpf(1.f - b1p);
        const float rb2 = __builtin_amdgcn_rcpf(1.f - b2p);
        float qc = 0.f, rr_ = 0.f;
        #pragma unroll
        for (int pp = 0; pp < 2; ++pp)
            #pragma unroll
            for (int T = 0; T < 2; ++T)
                #pragma unroll
                for (int t = 0; t < 4; ++t) {
                    const int j = pp * 8 + T * 4 + t;
                    const float a4v = (pp == 0) ? ((T == 0) ? acc00[t] : acc01[t])
                                                : ((T == 0) ? acc10[t] : acc11[t]);
                    const int arow = 16 * pp + 4 * lh + t;
                    const int col  = 32 * ks + 16 * T + lr;
                    const float xbj = s_xb[arow * NB + col];
                    const float c_  = cf[j];
                    qc  += c_ * (a4v - 2.f * xbj);
                    rr_ += fabsf(c_);
                    const float sgn = (c_ > 0.f) ? 1.f : ((c_ < 0.f) ? -1.f : 0.f);
                    const float gg  = c1c * (a4v - xbj) + c2c * sgn;
                    m_[j] = 0.9f * m_[j] + 0.1f * gg;
                    v_[j] = 0.999f * v_[j] + 0.001f * gg * gg;
                    const float den = __builtin_amdgcn_sqrtf(v_[j] * rb2) + 1e-8f;
                    cf[j] = c_ - 1e-3f * (m_[j] * rb1) * __builtin_amdgcn_rcpf(den);
                    const int wb = ((arow * NB + col) ^ ((arow & 7) << 3)) << 1;
                    const unsigned hb = bf16_hi(cf[j]);
                    const float    hf = __uint_as_float(hb << 16);
                    *(short*)(wrb + wb)         = (short)hb;
                    *(short*)(wrb + wb + 16384) = (short)bf16_hi(cf[j] - hf);
                }
        if (it + 1 < n_iter) {
            #pragma unroll
            for (int off = 32; off; off >>= 1) {
                qc  += __shfl_down(qc, off);
                rr_ += __shfl_down(rr_, off);
            }
            if (kg == 0) { s_redq[p][ks] = qc; s_redr[p][ks] = rr_; }
        }
    }

    // ---- post-loop consume round: conv at t = n_iter-2 (if not stopped) ----
    if (!use_prev && n_iter >= 2) {
        if (tid == 64) {
            const int itc = n_iter - 2;
            const int pc  = itc & 1;
            double Qt = 0.0, Rt = 0.0;
            #pragma unroll
            for (int i = 0; i < 8; ++i) {
                Qt += (double)s_redq[pc][i];
                Rt += (double)s_redr[pc][i];
            }
            if (itc == 0)
                sxtot = sxw[w*4+0] + sxw[w*4+1] + sxw[w*4+2] + sxw[w*4+3];
            const float loss = (float)((Qt + sxtot) / 32768.0 + 0.2 * (Rt / 8192.0));
            const float stat = fabsf(old_loss - loss) / old_loss;
            s_stop[0] = (stat < 1e-3f) ? 1 : 0;
        }
        __syncthreads();
        use_prev = s_stop[0];
    }

    // ---- output; on stop reconstruct pre-step coef by exact Adam-step undo ----
    {
        const float rb1e = __builtin_amdgcn_rcpf(1.f - b1p);
        const float rb2e = __builtin_amdgcn_rcpf(1.f - b2p);
        #pragma unroll
        for (int pp = 0; pp < 2; ++pp)
            #pragma unroll
            for (int T = 0; T < 2; ++T)
                #pragma unroll
                for (int t = 0; t < 4; ++t) {
                    const int j = pp * 8 + T * 4 + t;
                    float val = cf[j];
                    if (use_prev) {
                        const float den = __builtin_amdgcn_sqrtf(v_[j] * rb2e) + 1e-8f;
                        val += 1e-3f * (m_[j] * rb1e) * __builtin_amdgcn_rcpf(den);
                    }
                    const int row = 16 * pp + 4 * lh + t;
                    const int col = 32 * ks + 16 * T + lr;
                    out[((size_t)row * NB + col) * NW + w] = val;
                }
    }
}

// ---------------------------------------------------------------------------
extern "C" void kernel_launch(void* const* d_in, const int* in_sizes, int n_in,
                              void* d_out, int out_size, void* d_ws, size_t ws_size,
                              hipStream_t stream)
{
    const float* spec   = (const float*)d_in[0];
    const float* basis  = (const float*)d_in[1];
    const int* p_niter  = (const int*)d_in[2];
    const int* p_pad    = (const int*)d_in[3];
    const int* p_stride = (const int*)d_in[4];
    float* out = (float*)d_out;

    char* ws = (char*)d_ws;
    short*        Ghi  = (short*)ws;                      // 128 KB
    short*        Glo  = (short*)(ws + 131072);           // 128 KB
    double*       sxw  = (double*)(ws + 262144);          // 2016 B
    unsigned int* arr  = (unsigned int*)(ws + 264192);    // 252 B
    unsigned int* gbar = (unsigned int*)(ws + 264448);    // 4 B

    hipMemsetAsync(ws + 264192, 0, 512, stream);          // arr + gbar
    window_kernel<<<dim3(GRID), dim3(512), 0, stream>>>(
        spec, basis, Ghi, Glo, p_niter, p_pad, p_stride, sxw, arr, gbar, out);
}

// Round 7
// 474.933 us; speedup vs baseline: 8.1853x; 1.0832x over previous
//
#include <hip/hip_runtime.h>
#include <math.h>

// SparseCoding, round 20.
// Record: R13=245 (VALU GEMM, 252 blk), R14=244 (MFMA + SPILLS, 252 blk),
// R19=474 (MFMA, no spills, 63 blk -> latency-starved: MfmaUtil 2%, VALU 7%).
// Revised theory: R14's wall-invariance was the SPILLS (VGPR demand ~230 vs
// 128 cap), not a transport floor -- R13's 4 sibling blocks are XCD-colocated
// (bid%8 equal) and gpart is already 64B-exclusive per (it,w); only gcnt packs
// 16 windows x 8 XCDs per line (real ping-pong).
// R20 = R14 verbatim with exactly three changes:
//  1. G streamed from L2 as bf16 hi/lo PLANES (Gram-phase split, R19-proven
//     symmetric row-write = col-major B-frag layout). Removes the 128 G-VGPRs
//     -> per-thread demand ~95 < 128 cap -> NO spills (watch WRITE_SIZE).
//  2. gcnt re-indexed gidx(it,w) = (w&7)*384 + it*8 + (w>>3): every 64B line
//     holds only same-XCD windows -> no cross-XCD line bounce.
//  3. Nothing else: setup/xB (bit-identical R13 chains), lag-2 consume, dual
//     parity, last-man-out post, Adam, cfp, epilogue all byte-identical R14.
#define NB     256
#define NF     128
#define FT     1024
#define NW     63
#define TORIG  256
#define MAXIT  48
#define RPB    8
#define NBLK   4
#define GRID   256
#define GCNT_N (8 * MAXIT * 8)   // 3072 entries (w&7 x it x w>>3)

using f32x4  = __attribute__((ext_vector_type(4))) float;
using bf16x8 = __attribute__((ext_vector_type(8))) short;

// exchange layout (float4 index): k2*512 + row*64 + (cg ^ row)  [setup xB only]
__device__ __forceinline__ int xidx(int k2, int cg, int row) {
    return (k2 * 512 + row * 64 + (cg ^ row)) * 4;
}

// gcnt index: XCD-private 64B lines (windows with equal w&7 share a line)
__device__ __forceinline__ int gidx(int it, int w) {
    return (w & 7) * (MAXIT * 8) + it * 8 + (w >> 3);
}

// round-to-nearest-even fp32 -> bf16 bits (upper 16)
__device__ __forceinline__ unsigned bf16_hi(float x) {
    const unsigned u = __float_as_uint(x);
    return (u + 0x7fffu + ((u >> 16) & 1u)) >> 16;
}

__global__ __launch_bounds__(512, 2) void window_kernel(
    const float* __restrict__ spec,
    const float* __restrict__ basis,
    short* __restrict__ Ghi,             // ws: 256x256 bf16 hi plane
    short* __restrict__ Glo,             // ws: 256x256 bf16 lo plane
    const int* __restrict__ p_niter,
    const int* __restrict__ p_pad,
    const int* __restrict__ p_stride,
    double* __restrict__ sxbuf,          // [NW][NBLK]
    double* __restrict__ gpart,          // [MAXIT][NW][NBLK][2] (64B per (it,w))
    unsigned int* __restrict__ gcnt,     // [GCNT_N] arrivals + [GCNT_N]=gbar
    float* __restrict__ out)             // (32,256,63)
{
    __shared__ __align__(16) float s_p0[RPB * 2048];   // 64 KB xB exchange (setup)
    __shared__ __align__(16) float s_xn[RPB * FT];     // 32 KB staging + xB scratch
    __shared__ __align__(16) short A0[16 * NB];        // 8 KB stacked bf16 coef
    __shared__ __align__(16) short A1[16 * NB];        //   (hi rows 0-7, lo 8-15)
    __shared__ float  s_gred[2][NB];
    __shared__ float  s_mn[RPB], s_rng[RPB];
    __shared__ double s_dred[8];
    __shared__ float  s_redq[2][8], s_redr[2][8];
    __shared__ unsigned int s_wcnt[2];
    __shared__ int    s_stop[2];

    const int bid = blockIdx.x;
    const int yy  = bid >> 3;
    const int q   = yy & 3;
    const int w   = (bid & 7) + 8 * (yy >> 2);   // 4 blocks/window share bid%8 (XCD)
    const int tid = threadIdx.x;
    const int ks  = tid >> 6;                    // wave index
    const int kg  = tid & 63;
    const int r   = kg >> 3;                     // setup-phase owned row
    const int cgo = 8 * ks + (kg & 7);           // setup-phase owned colgroup
    const int n_iter = p_niter[0];
    unsigned int* gbar = gcnt + GCNT_N;

    // ================= fused Gram: block bid -> G row bid -> bf16 planes =========
    {
        const int c = tid & 255, jh = tid >> 8;
        float acc = 0.f;
        const float* bp = basis + (size_t)(jh * 512) * NB;
        #pragma unroll 16
        for (int j = 0; j < 512; ++j)
            acc = fmaf(bp[j * NB + bid], bp[j * NB + c], acc);
        s_gred[jh][c] = acc;
        __syncthreads();
        if (jh == 0) {
            const float g = s_gred[0][c] + s_gred[1][c];
            const unsigned hb = bf16_hi(g);
            const float    hf = __uint_as_float(hb << 16);
            Ghi[(size_t)bid * NB + c] = (short)hb;     // symmetric: row-write ==
            Glo[(size_t)bid * NB + c] = (short)bf16_hi(g - hf);  // col-major frag
        }
    }
    __threadfence();
    __syncthreads();
    if (tid == 0) atomicAdd(gbar, 1u);
    if (w >= NW) return;

    const int t0 = w * p_stride[0] - p_pad[0];

    // ================= stage raw window, min/max, normalize ======================
    #pragma unroll
    for (int i = 0; i < 16; ++i) {
        const int e = i * 512 + tid;
        const int b = e >> 10, jj = e & 1023;
        const int f = jj >> 3, t = jj & 7, tq = t0 + t;
        s_xn[b * FT + jj] = (tq >= 0 && tq < TORIG)
            ? spec[((size_t)(q * RPB + b) * NF + f) * TORIG + tq] : 0.f;
    }
    __syncthreads();
    {   // wave ks scans row ks
        float mn = __builtin_inff(), mx = -__builtin_inff();
        #pragma unroll
        for (int i = 0; i < 16; ++i) {
            const float v = s_xn[ks * FT + i * 64 + kg];
            mn = fminf(mn, v); mx = fmaxf(mx, v);
        }
        #pragma unroll
        for (int off = 32; off; off >>= 1) {
            mn = fminf(mn, __shfl_down(mn, off));
            mx = fmaxf(mx, __shfl_down(mx, off));
        }
        if (kg == 0) { s_mn[ks] = mn; s_rng[ks] = mx - mn; }
    }
    __syncthreads();
    double sx2p = 0.0;
    #pragma unroll
    for (int i = 0; i < 16; ++i) {
        const int e = i * 512 + tid;
        const int b = e >> 10, jj = e & 1023;
        const float v = (s_xn[b * FT + jj] - s_mn[b]) / s_rng[b];
        s_xn[b * FT + jj] = v;
        sx2p += (double)v * (double)v;
    }
    #pragma unroll
    for (int off = 32; off; off >>= 1) sx2p += __shfl_down(sx2p, off);
    if (kg == 0) s_dred[ks] = sx2p;
    __syncthreads();
    if (tid == 0) {
        double s = 0.0;
        #pragma unroll
        for (int i = 0; i < 8; ++i) s += s_dred[i];
        sxbuf[w * NBLK + q] = s;
        __threadfence();
    }

    // ====== xB = xnorm @ basis (R13 path, bit-identical; K-split partials) =======
    float xbp[RPB][4];
    #pragma unroll
    for (int b = 0; b < RPB; ++b)
        #pragma unroll
        for (int j = 0; j < 4; ++j) xbp[b][j] = 0.f;
    for (int i0 = 0; i0 < 128; i0 += 4) {
        const int jj = ks * 128 + i0;
        float4 bv[4];
        #pragma unroll
        for (int t = 0; t < 4; ++t)
            bv[t] = *(const float4*)(basis + (size_t)(jj + t) * NB + 4 * kg);
        #pragma unroll
        for (int b = 0; b < RPB; ++b) {
            const float4 x4 = *(const float4*)&s_xn[b * FT + jj];
            xbp[b][0] = fmaf(x4.x, bv[0].x, fmaf(x4.y, bv[1].x, fmaf(x4.z, bv[2].x, fmaf(x4.w, bv[3].x, xbp[b][0]))));
            xbp[b][1] = fmaf(x4.x, bv[0].y, fmaf(x4.y, bv[1].y, fmaf(x4.z, bv[2].y, fmaf(x4.w, bv[3].y, xbp[b][1]))));
            xbp[b][2] = fmaf(x4.x, bv[0].z, fmaf(x4.y, bv[1].z, fmaf(x4.z, bv[2].z, fmaf(x4.w, bv[3].z, xbp[b][2]))));
            xbp[b][3] = fmaf(x4.x, bv[0].w, fmaf(x4.y, bv[1].w, fmaf(x4.z, bv[2].w, fmaf(x4.w, bv[3].w, xbp[b][3]))));
        }
    }
    __syncthreads();
    #pragma unroll
    for (int b = 0; b < RPB; ++b)
        *(float4*)&s_p0[xidx(ks, kg, b)] =
            make_float4(xbp[b][0], xbp[b][1], xbp[b][2], xbp[b][3]);
    __syncthreads();
    float xBo[4] = {0.f, 0.f, 0.f, 0.f};
    #pragma unroll
    for (int k2 = 0; k2 < 8; ++k2) {
        const float4 p4 = *(const float4*)&s_p0[xidx(k2, cgo, r)];
        xBo[0] += p4.x; xBo[1] += p4.y; xBo[2] += p4.z; xBo[3] += p4.w;
    }
    // redistribute xB to the MFMA C layout via s_xn scratch (staging is dead)
    *(float4*)&s_xn[r * NB + 4 * cgo] = make_float4(xBo[0], xBo[1], xBo[2], xBo[3]);

    // ================= wait for G planes; init block-local sync ==================
    if (tid == 0) {
        while (__hip_atomic_load(gbar, __ATOMIC_ACQUIRE, __HIP_MEMORY_SCOPE_AGENT) < (unsigned)GRID)
            __builtin_amdgcn_s_sleep(1);
    }
    if (tid == 64) { s_wcnt[0] = 0; s_wcnt[1] = 0; s_stop[0] = 0; s_stop[1] = 0; }
    __syncthreads();

    // ============== MFMA-layout ownership & fragment constants ===================
    const int lr  = kg & 15;        // C col within tile
    const int lh  = kg >> 4;        // lane group 0..3
    const int hlf = kg >> 5;        // 0 = hi rows, 1 = lo rows (duplicate owner)

    float xB[8];
    #pragma unroll
    for (int T = 0; T < 2; ++T)
        #pragma unroll
        for (int t = 0; t < 4; ++t)
            xB[4*T + t] = s_xn[(4*(lh & 1) + t) * NB + 32*ks + 16*T + lr];

    // G plane pointers (B-frag: col = lane&15 -> row c0 of plane; k contiguous)
    const int c0 = 32 * ks + lr;
    const short* ghp = Ghi + (size_t)c0 * NB + 8 * lh;   // +32*kk per step; +4096 = T1
    const short* glp = Glo + (size_t)c0 * NB + 8 * lh;

    // A-tile addressing. A layout: row = lane&15, k = 8*(lane>>4)+b.
    // Swizzle: short-idx ^= (row&7)<<3  (16B granule spread across banks).
    unsigned awaddr[8];
    #pragma unroll
    for (int T = 0; T < 2; ++T)
        #pragma unroll
        for (int t = 0; t < 4; ++t) {
            const int hr  = 4*(lh & 1) + t;
            const int col = 32*ks + 16*T + lr;
            awaddr[4*T + t] = (unsigned)((((hr * NB + col) ^ ((hr & 7) << 3)) * 2)
                                         + (hlf ? 4096 : 0));
        }
    const unsigned abase = (unsigned)(((lr * NB + lh * 8) ^ ((lr & 7) << 3)) * 2);

    // ================= init owned coef / Adam; write A0 ==========================
    const float C0 = 0.5f / 256.f;
    float cf[8], cfp[8], m_[8], v_[8];
    #pragma unroll
    for (int j = 0; j < 8; ++j) { cf[j] = C0; cfp[j] = C0; m_[j] = 0.f; v_[j] = 0.f; }
    {
        const short vh  = (short)bf16_hi(C0);     // C0 = 2^-9: exact, lo = 0
        const short val = hlf ? (short)0 : vh;
        #pragma unroll
        for (int j = 0; j < 8; ++j)
            *(short*)((char*)A0 + awaddr[j]) = val;
    }
    float b1p = 1.f, b2p = 1.f;
    float old_loss = 1e-10f;      // tid64 only
    double sxtot = 0.0;           // tid64 only
    const float c1c = 2.f / 32768.f, c2c = 0.2f / 8192.f;
    int use_prev = 0;

    for (int it = 0; it < n_iter; ++it) {
        const int p = it & 1;
        const char* rdb = (const char*)(p ? A1 : A0);
        char*       wrb = (char*)(p ? A0 : A1);

        __syncthreads();          // barrier 1: A[rd] writes (prev iter) visible

        // ---- MFMA: Astack(16x256) @ (Ghi+Glo) streamed from L2 ----
        f32x4 a1[2], a2[2];
        const f32x4 z4 = {0.f, 0.f, 0.f, 0.f};
        a1[0] = z4; a1[1] = z4; a2[0] = z4; a2[1] = z4;
        #pragma unroll 2
        for (int kk = 0; kk < 8; ++kk) {
            const bf16x8 Gh0 = *(const bf16x8*)(ghp + 32 * kk);
            const bf16x8 Gl0 = *(const bf16x8*)(glp + 32 * kk);
            const bf16x8 Gh1 = *(const bf16x8*)(ghp + 4096 + 32 * kk);
            const bf16x8 Gl1 = *(const bf16x8*)(glp + 4096 + 32 * kk);
            const bf16x8 af  = *(const bf16x8*)(rdb + (abase ^ (unsigned)(kk << 6)));
            a1[0] = __builtin_amdgcn_mfma_f32_16x16x32_bf16(af, Gh0, a1[0], 0, 0, 0);
            a2[0] = __builtin_amdgcn_mfma_f32_16x16x32_bf16(af, Gl0, a2[0], 0, 0, 0);
            a1[1] = __builtin_amdgcn_mfma_f32_16x16x32_bf16(af, Gh1, a1[1], 0, 0, 0);
            a2[1] = __builtin_amdgcn_mfma_f32_16x16x32_bf16(af, Gl1, a2[1], 0, 0, 0);
        }
        float a4[8];
        #pragma unroll
        for (int T = 0; T < 2; ++T)
            #pragma unroll
            for (int t = 0; t < 4; ++t) {
                const float s = a1[T][t] + a2[T][t];
                a4[4*T + t] = s + __shfl_xor(s, 32);   // hi-row + lo-row halves
            }

        // ---- tid64: LAG-2 consume (R13 machinery; XCD-private gcnt line) ----
        if (tid == 64 && it >= 2) {
            const int itc = it - 2;
            while (__hip_atomic_load(&gcnt[gidx(itc, w)], __ATOMIC_ACQUIRE,
                                     __HIP_MEMORY_SCOPE_AGENT) < (unsigned)NBLK)
                __builtin_amdgcn_s_sleep(1);
            const size_t pbm = ((size_t)itc * NW + w) * NBLK;
            double Qt = 0.0, Rt = 0.0;
            #pragma unroll
            for (int i = 0; i < NBLK; ++i) {
                Qt += gpart[(pbm + i) * 2 + 0];
                Rt += gpart[(pbm + i) * 2 + 1];
            }
            if (itc == 0)
                sxtot = sxbuf[w * NBLK + 0] + sxbuf[w * NBLK + 1] +
                        sxbuf[w * NBLK + 2] + sxbuf[w * NBLK + 3];
            const float loss = (float)((Qt + sxtot) / 32768.0 + 0.2 * (Rt / 8192.0));
            const float stat = fabsf(old_loss - loss) / old_loss;
            old_loss = loss;
            s_stop[p] = (stat < 1e-3f) ? 1 : 0;
        }

        __syncthreads();          // THE barrier: s_stop[p] visible

        if (s_stop[p]) { use_prev = 1; break; }   // t*=it-2 -> answer = cfp

        // ---- loss partials + last-man-out block post (skip on final iter) ----
        if (it + 1 < n_iter) {
            float qc = 0.f, rr = 0.f;
            #pragma unroll
            for (int j = 0; j < 8; ++j) {
                qc += cf[j] * (a4[j] - 2.f * xB[j]);
                rr += fabsf(cf[j]);
            }
            if (kg >= 32) { qc = 0.f; rr = 0.f; }   // upper half duplicates
            #pragma unroll
            for (int off = 32; off; off >>= 1) {
                qc += __shfl_down(qc, off);
                rr += __shfl_down(rr, off);
            }
            if (kg == 0) {
                s_redq[p][ks] = qc; s_redr[p][ks] = rr;
                __threadfence_block();
                const unsigned old = __hip_atomic_fetch_add(&s_wcnt[p], 1u,
                                        __ATOMIC_ACQ_REL, __HIP_MEMORY_SCOPE_WORKGROUP);
                if (old == 7u) {
                    float Q = 0.f, R = 0.f;
                    #pragma unroll
                    for (int i = 0; i < 8; ++i) { Q += s_redq[p][i]; R += s_redr[p][i]; }
                    s_wcnt[p] = 0u;
                    const size_t pb = ((size_t)it * NW + w) * NBLK;
                    gpart[(pb + q) * 2 + 0] = (double)Q;
                    gpart[(pb + q) * 2 + 1] = (double)R;
                    __hip_atomic_fetch_add(&gcnt[gidx(it, w)], 1u,
                                           __ATOMIC_RELEASE, __HIP_MEMORY_SCOPE_AGENT);
                }
            }
        }

        // ---- Adam update (fast rcp/sqrt; cfp snapshot first) ----
        b1p *= 0.9f; b2p *= 0.999f;
        const float rb1 = __builtin_amdgcn_rcpf(1.f - b1p);
        const float rb2 = __builtin_amdgcn_rcpf(1.f - b2p);
        #pragma unroll
        for (int j = 0; j < 8; ++j) {
            const float c_ = cf[j];
            cfp[j] = c_;
            const float sgn = (c_ > 0.f) ? 1.f : ((c_ < 0.f) ? -1.f : 0.f);
            const float gg = c1c * (a4[j] - xB[j]) + c2c * sgn;
            m_[j] = 0.9f * m_[j] + 0.1f * gg;
            v_[j] = 0.999f * v_[j] + 0.001f * gg * gg;
            const float den = __builtin_amdgcn_sqrtf(v_[j] * rb2) + 1e-8f;
            cf[j] = c_ - 1e-3f * (m_[j] * rb1) * __builtin_amdgcn_rcpf(den);
        }

        // ---- bf16 hi/lo split of new coef -> next A buffer ----
        #pragma unroll
        for (int j = 0; j < 8; ++j) {
            const unsigned hb = bf16_hi(cf[j]);
            const float    hf = __uint_as_float(hb << 16);
            const unsigned lb = bf16_hi(cf[j] - hf);
            *(short*)(wrb + awaddr[j]) = (short)(hlf ? lb : hb);
        }
    }

    // ---- post-loop consume round: conv at t = n_iter-2 (if not already stopped) ----
    if (!use_prev && n_iter >= 2) {
        if (tid == 64) {
            const int itc = n_iter - 2;
            while (__hip_atomic_load(&gcnt[gidx(itc, w)], __ATOMIC_ACQUIRE,
                                     __HIP_MEMORY_SCOPE_AGENT) < (unsigned)NBLK)
                __builtin_amdgcn_s_sleep(1);
            const size_t pbm = ((size_t)itc * NW + w) * NBLK;
            double Qt = 0.0, Rt = 0.0;
            #pragma unroll
            for (int i = 0; i < NBLK; ++i) {
                Qt += gpart[(pbm + i) * 2 + 0];
                Rt += gpart[(pbm + i) * 2 + 1];
            }
            if (itc == 0)
                sxtot = sxbuf[w * NBLK + 0] + sxbuf[w * NBLK + 1] +
                        sxbuf[w * NBLK + 2] + sxbuf[w * NBLK + 3];
            const float loss = (float)((Qt + sxtot) / 32768.0 + 0.2 * (Rt / 8192.0));
            const float stat = fabsf(old_loss - loss) / old_loss;
            s_stop[0] = (stat < 1e-3f) ? 1 : 0;
        }
        __syncthreads();
        use_prev = s_stop[0];
    }

    // ---- out[b][k][w]: lanes<32 own rows 0-7 (upper half duplicates) ----
    if (kg < 32) {
        #pragma unroll
        for (int T = 0; T < 2; ++T)
            #pragma unroll
            for (int t = 0; t < 4; ++t)
                out[((size_t)(q * RPB + 4*lh + t) * NB + 32*ks + 16*T + lr) * NW + w] =
                    use_prev ? cfp[4*T + t] : cf[4*T + t];
    }
}

// ---------------------------------------------------------------------------
extern "C" void kernel_launch(void* const* d_in, const int* in_sizes, int n_in,
                              void* d_out, int out_size, void* d_ws, size_t ws_size,
                              hipStream_t stream)
{
    const float* spec   = (const float*)d_in[0];
    const float* basis  = (const float*)d_in[1];
    const int* p_niter  = (const int*)d_in[2];
    const int* p_pad    = (const int*)d_in[3];
    const int* p_stride = (const int*)d_in[4];
    float* out = (float*)d_out;

    char* ws = (char*)d_ws;
    short*        Ghi   = (short*)ws;                     // 128 KB
    short*        Glo   = (short*)(ws + 131072);          // 128 KB
    double*       sxbuf = (double*)(ws + 262144);         // 2016 B (pad 4 KB)
    double*       gpart = (double*)(ws + 266240);         // 193536 B
    unsigned int* gcnt  = (unsigned int*)(ws + 266240 + 193536); // GCNT_N+1 u32

    hipMemsetAsync(gcnt, 0, (GCNT_N + 1) * sizeof(unsigned int), stream);
    window_kernel<<<dim3(GRID), dim3(512), 0, stream>>>(
        spec, basis, Ghi, Glo, p_niter, p_pad, p_stride, sxbuf, gpart, gcnt, out);
}

// Round 8
// 376.070 us; speedup vs baseline: 10.3371x; 1.2629x over previous
//
#include <hip/hip_runtime.h>
#include <math.h>

// SparseCoding, round 21.
// R20 post-mortem (434 us, VGPR 88 = NO spills, WRITE back to R13's 16.6MB):
// the MFMA loop streams G from L2 with nothing to hide it -- per CU 512KB/iter
// (~3.5us BW floor) + exposed ~200cyc chains; R13 hid the same traffic under
// ~2100cyc of VALU issue. Fix: G-hi RESIDENT IN LDS.
// R21 = R20 with three changes:
//  1. 144KB LDS arena: Ghi plane (128KB) copied once from ws into LDS with the
//     A-tile XOR-granule swizzle (writer: granule g -> g ^ ((g>>5)&7); reader:
//     short_idx ^ ((c0&7)<<3)). Forces 1 block/CU (~146KB total). 3/4 of the
//     per-kk operand stream becomes ds_read (~120cyc, pipelined).
//  2. Glo (2^-9 correction, 1/4 of MFMAs) stays on L2 with a depth-2 rotating
//     prefetch (static kk&1 indices under full unroll -> registers, rule #20).
//     Per-CU L2 traffic drops 4x to 128KB/iter (~0.9us).
//  3. Setup s_p0/s_xn alias the arena ([0,96KB), dead before the Ghi copy;
//     one extra barrier after the xB register load guards the overwrite).
// Machinery identical to R20: 252 blocks (4/window, XCD-colocated), bit-exact
// R13 setup/xB, lag-2 consume, XCD-private gcnt lines, dual parity,
// last-man-out post, Adam + cfp, epilogue.
#define NB     256
#define NF     128
#define FT     1024
#define NW     63
#define TORIG  256
#define MAXIT  48
#define RPB    8
#define NBLK   4
#define GRID   256
#define GCNT_N (8 * MAXIT * 8)   // 3072 entries (w&7 x it x w>>3)

using f32x4  = __attribute__((ext_vector_type(4))) float;
using bf16x8 = __attribute__((ext_vector_type(8))) short;

// exchange layout (float4 index): k2*512 + row*64 + (cg ^ row)  [setup xB only]
__device__ __forceinline__ int xidx(int k2, int cg, int row) {
    return (k2 * 512 + row * 64 + (cg ^ row)) * 4;
}

// gcnt index: XCD-private 64B lines (windows with equal w&7 share a line)
__device__ __forceinline__ int gidx(int it, int w) {
    return (w & 7) * (MAXIT * 8) + it * 8 + (w >> 3);
}

// round-to-nearest-even fp32 -> bf16 bits (upper 16)
__device__ __forceinline__ unsigned bf16_hi(float x) {
    const unsigned u = __float_as_uint(x);
    return (u + 0x7fffu + ((u >> 16) & 1u)) >> 16;
}

__global__ __launch_bounds__(512, 1) void window_kernel(
    const float* __restrict__ spec,
    const float* __restrict__ basis,
    short* __restrict__ Ghi,             // ws: 256x256 bf16 hi plane
    short* __restrict__ Glo,             // ws: 256x256 bf16 lo plane
    const int* __restrict__ p_niter,
    const int* __restrict__ p_pad,
    const int* __restrict__ p_stride,
    double* __restrict__ sxbuf,          // [NW][NBLK]
    double* __restrict__ gpart,          // [MAXIT][NW][NBLK][2] (64B per (it,w))
    unsigned int* __restrict__ gcnt,     // [GCNT_N] arrivals + [GCNT_N]=gbar
    float* __restrict__ out)             // (32,256,63)
{
    // arena 144KB: loop = [Ghi-LDS 128KB][A0 8KB][A1 8KB]
    //              setup aliases [0,96KB): s_p0 64KB + s_xn 32KB (dead by copy)
    __shared__ __align__(16) char arena[147456];
    float* const s_p0 = (float*)arena;
    float* const s_xn = (float*)(arena + 65536);
    short* const A0   = (short*)(arena + 131072);
    short* const A1   = (short*)(arena + 139264);
    const char* const GLc = (const char*)arena;    // swizzled Ghi plane (loop)
    __shared__ float  s_gred[2][NB];
    __shared__ float  s_mn[RPB], s_rng[RPB];
    __shared__ double s_dred[8];
    __shared__ float  s_redq[2][8], s_redr[2][8];
    __shared__ unsigned int s_wcnt[2];
    __shared__ int    s_stop[2];

    const int bid = blockIdx.x;
    const int yy  = bid >> 3;
    const int q   = yy & 3;
    const int w   = (bid & 7) + 8 * (yy >> 2);   // 4 blocks/window share bid%8 (XCD)
    const int tid = threadIdx.x;
    const int ks  = tid >> 6;                    // wave index
    const int kg  = tid & 63;
    const int r   = kg >> 3;                     // setup-phase owned row
    const int cgo = 8 * ks + (kg & 7);           // setup-phase owned colgroup
    const int n_iter = p_niter[0];
    unsigned int* gbar = gcnt + GCNT_N;

    // ================= fused Gram: block bid -> G row bid -> bf16 planes =========
    {
        const int c = tid & 255, jh = tid >> 8;
        float acc = 0.f;
        const float* bp = basis + (size_t)(jh * 512) * NB;
        #pragma unroll 16
        for (int j = 0; j < 512; ++j)
            acc = fmaf(bp[j * NB + bid], bp[j * NB + c], acc);
        s_gred[jh][c] = acc;
        __syncthreads();
        if (jh == 0) {
            const float g = s_gred[0][c] + s_gred[1][c];
            const unsigned hb = bf16_hi(g);
            const float    hf = __uint_as_float(hb << 16);
            Ghi[(size_t)bid * NB + c] = (short)hb;     // symmetric: row-write ==
            Glo[(size_t)bid * NB + c] = (short)bf16_hi(g - hf);  // col-major frag
        }
    }
    __threadfence();
    __syncthreads();
    if (tid == 0) atomicAdd(gbar, 1u);
    if (w >= NW) return;

    const int t0 = w * p_stride[0] - p_pad[0];

    // ================= stage raw window, min/max, normalize ======================
    #pragma unroll
    for (int i = 0; i < 16; ++i) {
        const int e = i * 512 + tid;
        const int b = e >> 10, jj = e & 1023;
        const int f = jj >> 3, t = jj & 7, tq = t0 + t;
        s_xn[b * FT + jj] = (tq >= 0 && tq < TORIG)
            ? spec[((size_t)(q * RPB + b) * NF + f) * TORIG + tq] : 0.f;
    }
    __syncthreads();
    {   // wave ks scans row ks
        float mn = __builtin_inff(), mx = -__builtin_inff();
        #pragma unroll
        for (int i = 0; i < 16; ++i) {
            const float v = s_xn[ks * FT + i * 64 + kg];
            mn = fminf(mn, v); mx = fmaxf(mx, v);
        }
        #pragma unroll
        for (int off = 32; off; off >>= 1) {
            mn = fminf(mn, __shfl_down(mn, off));
            mx = fmaxf(mx, __shfl_down(mx, off));
        }
        if (kg == 0) { s_mn[ks] = mn; s_rng[ks] = mx - mn; }
    }
    __syncthreads();
    double sx2p = 0.0;
    #pragma unroll
    for (int i = 0; i < 16; ++i) {
        const int e = i * 512 + tid;
        const int b = e >> 10, jj = e & 1023;
        const float v = (s_xn[b * FT + jj] - s_mn[b]) / s_rng[b];
        s_xn[b * FT + jj] = v;
        sx2p += (double)v * (double)v;
    }
    #pragma unroll
    for (int off = 32; off; off >>= 1) sx2p += __shfl_down(sx2p, off);
    if (kg == 0) s_dred[ks] = sx2p;
    __syncthreads();
    if (tid == 0) {
        double s = 0.0;
        #pragma unroll
        for (int i = 0; i < 8; ++i) s += s_dred[i];
        sxbuf[w * NBLK + q] = s;
        __threadfence();
    }

    // ====== xB = xnorm @ basis (R13 path, bit-identical; K-split partials) =======
    float xbp[RPB][4];
    #pragma unroll
    for (int b = 0; b < RPB; ++b)
        #pragma unroll
        for (int j = 0; j < 4; ++j) xbp[b][j] = 0.f;
    for (int i0 = 0; i0 < 128; i0 += 4) {
        const int jj = ks * 128 + i0;
        float4 bv[4];
        #pragma unroll
        for (int t = 0; t < 4; ++t)
            bv[t] = *(const float4*)(basis + (size_t)(jj + t) * NB + 4 * kg);
        #pragma unroll
        for (int b = 0; b < RPB; ++b) {
            const float4 x4 = *(const float4*)&s_xn[b * FT + jj];
            xbp[b][0] = fmaf(x4.x, bv[0].x, fmaf(x4.y, bv[1].x, fmaf(x4.z, bv[2].x, fmaf(x4.w, bv[3].x, xbp[b][0]))));
            xbp[b][1] = fmaf(x4.x, bv[0].y, fmaf(x4.y, bv[1].y, fmaf(x4.z, bv[2].y, fmaf(x4.w, bv[3].y, xbp[b][1]))));
            xbp[b][2] = fmaf(x4.x, bv[0].z, fmaf(x4.y, bv[1].z, fmaf(x4.z, bv[2].z, fmaf(x4.w, bv[3].z, xbp[b][2]))));
            xbp[b][3] = fmaf(x4.x, bv[0].w, fmaf(x4.y, bv[1].w, fmaf(x4.z, bv[2].w, fmaf(x4.w, bv[3].w, xbp[b][3]))));
        }
    }
    __syncthreads();
    #pragma unroll
    for (int b = 0; b < RPB; ++b)
        *(float4*)&s_p0[xidx(ks, kg, b)] =
            make_float4(xbp[b][0], xbp[b][1], xbp[b][2], xbp[b][3]);
    __syncthreads();
    float xBo[4] = {0.f, 0.f, 0.f, 0.f};
    #pragma unroll
    for (int k2 = 0; k2 < 8; ++k2) {
        const float4 p4 = *(const float4*)&s_p0[xidx(k2, cgo, r)];
        xBo[0] += p4.x; xBo[1] += p4.y; xBo[2] += p4.z; xBo[3] += p4.w;
    }
    // redistribute xB to the MFMA C layout via s_xn scratch (staging is dead)
    __syncthreads();
    *(float4*)&s_xn[r * NB + 4 * cgo] = make_float4(xBo[0], xBo[1], xBo[2], xBo[3]);

    // ================= wait for G planes; init block-local sync ==================
    if (tid == 0) {
        while (__hip_atomic_load(gbar, __ATOMIC_ACQUIRE, __HIP_MEMORY_SCOPE_AGENT) < (unsigned)GRID)
            __builtin_amdgcn_s_sleep(1);
    }
    if (tid == 64) { s_wcnt[0] = 0; s_wcnt[1] = 0; s_stop[0] = 0; s_stop[1] = 0; }
    __syncthreads();

    // ============== MFMA-layout ownership & fragment constants ===================
    const int lr  = kg & 15;        // C col within tile
    const int lh  = kg >> 4;        // lane group 0..3
    const int hlf = kg >> 5;        // 0 = hi rows, 1 = lo rows (duplicate owner)

    float xB[8];
    #pragma unroll
    for (int T = 0; T < 2; ++T)
        #pragma unroll
        for (int t = 0; t < 4; ++t)
            xB[4*T + t] = s_xn[(4*(lh & 1) + t) * NB + 32*ks + 16*T + lr];

    __syncthreads();   // xB reads done -> arena [0,131072) reusable for Ghi-LDS

    // ---- one-time Ghi plane -> LDS, XOR-granule swizzled (writer side) ----
    // granule g (16B): row = g>>5; dst granule = g ^ (row&7). Matches reader
    // short_idx ^ ((row&7)<<3).
    for (int g = tid; g < 8192; g += 512) {
        const int dg = g ^ ((g >> 5) & 7);
        *(float4*)(arena + (size_t)dg * 16) =
            *(const float4*)((const char*)Ghi + (size_t)g * 16);
    }

    // G columns owned by this wave: c0 (T0) and c0+16 (T1)
    const int c0   = 32 * ks + lr;
    const int swzg = (c0 & 7) << 3;
    const short* glp = Glo + (size_t)c0 * NB + 8 * lh;   // +32kk ; +4096 = T1

    // A-tile addressing. A layout: row = lane&15, k = 8*(lane>>4)+b.
    // Swizzle: short-idx ^= (row&7)<<3  (16B granule spread across banks).
    unsigned awaddr[8];
    #pragma unroll
    for (int T = 0; T < 2; ++T)
        #pragma unroll
        for (int t = 0; t < 4; ++t) {
            const int hr  = 4*(lh & 1) + t;
            const int col = 32*ks + 16*T + lr;
            awaddr[4*T + t] = (unsigned)((((hr * NB + col) ^ ((hr & 7) << 3)) * 2)
                                         + (hlf ? 4096 : 0));
        }
    const unsigned abase = (unsigned)(((lr * NB + lh * 8) ^ ((lr & 7) << 3)) * 2);

    // ================= init owned coef / Adam; write A0 ==========================
    const float C0 = 0.5f / 256.f;
    float cf[8], cfp[8], m_[8], v_[8];
    #pragma unroll
    for (int j = 0; j < 8; ++j) { cf[j] = C0; cfp[j] = C0; m_[j] = 0.f; v_[j] = 0.f; }
    {
        const short vh  = (short)bf16_hi(C0);     // C0 = 2^-9: exact, lo = 0
        const short val = hlf ? (short)0 : vh;
        #pragma unroll
        for (int j = 0; j < 8; ++j)
            *(short*)((char*)A0 + awaddr[j]) = val;
    }
    float b1p = 1.f, b2p = 1.f;
    float old_loss = 1e-10f;      // tid64 only
    double sxtot = 0.0;           // tid64 only
    const float c1c = 2.f / 32768.f, c2c = 0.2f / 8192.f;
    int use_prev = 0;

    for (int it = 0; it < n_iter; ++it) {
        const int p = it & 1;
        const char* rdb = (const char*)(p ? A1 : A0);
        char*       wrb = (char*)(p ? A0 : A1);

        __syncthreads();          // barrier 1: A[rd] + (it=0) Ghi-LDS visible

        // ---- MFMA: Astack(16x256) @ (Ghi[LDS] + Glo[L2, depth-2 prefetch]) ----
        f32x4 a1[2], a2[2];
        const f32x4 z4 = {0.f, 0.f, 0.f, 0.f};
        a1[0] = z4; a1[1] = z4; a2[0] = z4; a2[1] = z4;
        bf16x8 ql0[2], ql1[2];
        ql0[0] = *(const bf16x8*)(glp);
        ql1[0] = *(const bf16x8*)(glp + 4096);
        ql0[1] = *(const bf16x8*)(glp + 32);
        ql1[1] = *(const bf16x8*)(glp + 4096 + 32);
        #pragma unroll
        for (int kk = 0; kk < 8; ++kk) {
            const bf16x8 Gl0 = ql0[kk & 1];
            const bf16x8 Gl1 = ql1[kk & 1];
            if (kk + 2 < 8) {
                ql0[kk & 1] = *(const bf16x8*)(glp + 32 * (kk + 2));
                ql1[kk & 1] = *(const bf16x8*)(glp + 4096 + 32 * (kk + 2));
            }
            const int gsh = ((c0 * 256 + 8 * lh + 32 * kk) ^ swzg) << 1;
            const bf16x8 Gh0 = *(const bf16x8*)(GLc + gsh);
            const bf16x8 Gh1 = *(const bf16x8*)(GLc + gsh + 8192);
            const bf16x8 af  = *(const bf16x8*)(rdb + (abase ^ (unsigned)(kk << 6)));
            a1[0] = __builtin_amdgcn_mfma_f32_16x16x32_bf16(af, Gh0, a1[0], 0, 0, 0);
            a2[0] = __builtin_amdgcn_mfma_f32_16x16x32_bf16(af, Gl0, a2[0], 0, 0, 0);
            a1[1] = __builtin_amdgcn_mfma_f32_16x16x32_bf16(af, Gh1, a1[1], 0, 0, 0);
            a2[1] = __builtin_amdgcn_mfma_f32_16x16x32_bf16(af, Gl1, a2[1], 0, 0, 0);
        }
        float a4[8];
        #pragma unroll
        for (int T = 0; T < 2; ++T)
            #pragma unroll
            for (int t = 0; t < 4; ++t) {
                const float s = a1[T][t] + a2[T][t];
                a4[4*T + t] = s + __shfl_xor(s, 32);   // hi-row + lo-row halves
            }

        // ---- tid64: LAG-2 consume (R13 machinery; XCD-private gcnt line) ----
        if (tid == 64 && it >= 2) {
            const int itc = it - 2;
            while (__hip_atomic_load(&gcnt[gidx(itc, w)], __ATOMIC_ACQUIRE,
                                     __HIP_MEMORY_SCOPE_AGENT) < (unsigned)NBLK)
                __builtin_amdgcn_s_sleep(1);
            const size_t pbm = ((size_t)itc * NW + w) * NBLK;
            double Qt = 0.0, Rt = 0.0;
            #pragma unroll
            for (int i = 0; i < NBLK; ++i) {
                Qt += gpart[(pbm + i) * 2 + 0];
                Rt += gpart[(pbm + i) * 2 + 1];
            }
            if (itc == 0)
                sxtot = sxbuf[w * NBLK + 0] + sxbuf[w * NBLK + 1] +
                        sxbuf[w * NBLK + 2] + sxbuf[w * NBLK + 3];
            const float loss = (float)((Qt + sxtot) / 32768.0 + 0.2 * (Rt / 8192.0));
            const float stat = fabsf(old_loss - loss) / old_loss;
            old_loss = loss;
            s_stop[p] = (stat < 1e-3f) ? 1 : 0;
        }

        __syncthreads();          // THE barrier: s_stop[p] visible

        if (s_stop[p]) { use_prev = 1; break; }   // t*=it-2 -> answer = cfp

        // ---- loss partials + last-man-out block post (skip on final iter) ----
        if (it + 1 < n_iter) {
            float qc = 0.f, rr = 0.f;
            #pragma unroll
            for (int j = 0; j < 8; ++j) {
                qc += cf[j] * (a4[j] - 2.f * xB[j]);
                rr += fabsf(cf[j]);
            }
            if (kg >= 32) { qc = 0.f; rr = 0.f; }   // upper half duplicates
            #pragma unroll
            for (int off = 32; off; off >>= 1) {
                qc += __shfl_down(qc, off);
                rr += __shfl_down(rr, off);
            }
            if (kg == 0) {
                s_redq[p][ks] = qc; s_redr[p][ks] = rr;
                __threadfence_block();
                const unsigned old = __hip_atomic_fetch_add(&s_wcnt[p], 1u,
                                        __ATOMIC_ACQ_REL, __HIP_MEMORY_SCOPE_WORKGROUP);
                if (old == 7u) {
                    float Q = 0.f, R = 0.f;
                    #pragma unroll
                    for (int i = 0; i < 8; ++i) { Q += s_redq[p][i]; R += s_redr[p][i]; }
                    s_wcnt[p] = 0u;
                    const size_t pb = ((size_t)it * NW + w) * NBLK;
                    gpart[(pb + q) * 2 + 0] = (double)Q;
                    gpart[(pb + q) * 2 + 1] = (double)R;
                    __hip_atomic_fetch_add(&gcnt[gidx(it, w)], 1u,
                                           __ATOMIC_RELEASE, __HIP_MEMORY_SCOPE_AGENT);
                }
            }
        }

        // ---- Adam update (fast rcp/sqrt; cfp snapshot first) ----
        b1p *= 0.9f; b2p *= 0.999f;
        const float rb1 = __builtin_amdgcn_rcpf(1.f - b1p);
        const float rb2 = __builtin_amdgcn_rcpf(1.f - b2p);
        #pragma unroll
        for (int j = 0; j < 8; ++j) {
            const float c_ = cf[j];
            cfp[j] = c_;
            const float sgn = (c_ > 0.f) ? 1.f : ((c_ < 0.f) ? -1.f : 0.f);
            const float gg = c1c * (a4[j] - xB[j]) + c2c * sgn;
            m_[j] = 0.9f * m_[j] + 0.1f * gg;
            v_[j] = 0.999f * v_[j] + 0.001f * gg * gg;
            const float den = __builtin_amdgcn_sqrtf(v_[j] * rb2) + 1e-8f;
            cf[j] = c_ - 1e-3f * (m_[j] * rb1) * __builtin_amdgcn_rcpf(den);
        }

        // ---- bf16 hi/lo split of new coef -> next A buffer ----
        #pragma unroll
        for (int j = 0; j < 8; ++j) {
            const unsigned hb = bf16_hi(cf[j]);
            const float    hf = __uint_as_float(hb << 16);
            const unsigned lb = bf16_hi(cf[j] - hf);
            *(short*)(wrb + awaddr[j]) = (short)(hlf ? lb : hb);
        }
    }

    // ---- post-loop consume round: conv at t = n_iter-2 (if not already stopped) ----
    if (!use_prev && n_iter >= 2) {
        if (tid == 64) {
            const int itc = n_iter - 2;
            while (__hip_atomic_load(&gcnt[gidx(itc, w)], __ATOMIC_ACQUIRE,
                                     __HIP_MEMORY_SCOPE_AGENT) < (unsigned)NBLK)
                __builtin_amdgcn_s_sleep(1);
            const size_t pbm = ((size_t)itc * NW + w) * NBLK;
            double Qt = 0.0, Rt = 0.0;
            #pragma unroll
            for (int i = 0; i < NBLK; ++i) {
                Qt += gpart[(pbm + i) * 2 + 0];
                Rt += gpart[(pbm + i) * 2 + 1];
            }
            if (itc == 0)
                sxtot = sxbuf[w * NBLK + 0] + sxbuf[w * NBLK + 1] +
                        sxbuf[w * NBLK + 2] + sxbuf[w * NBLK + 3];
            const float loss = (float)((Qt + sxtot) / 32768.0 + 0.2 * (Rt / 8192.0));
            const float stat = fabsf(old_loss - loss) / old_loss;
            s_stop[0] = (stat < 1e-3f) ? 1 : 0;
        }
        __syncthreads();
        use_prev = s_stop[0];
    }

    // ---- out[b][k][w]: lanes<32 own rows 0-7 (upper half duplicates) ----
    if (kg < 32) {
        #pragma unroll
        for (int T = 0; T < 2; ++T)
            #pragma unroll
            for (int t = 0; t < 4; ++t)
                out[((size_t)(q * RPB + 4*lh + t) * NB + 32*ks + 16*T + lr) * NW + w] =
                    use_prev ? cfp[4*T + t] : cf[4*T + t];
    }
}

// ---------------------------------------------------------------------------
extern "C" void kernel_launch(void* const* d_in, const int* in_sizes, int n_in,
                              void* d_out, int out_size, void* d_ws, size_t ws_size,
                              hipStream_t stream)
{
    const float* spec   = (const float*)d_in[0];
    const float* basis  = (const float*)d_in[1];
    const int* p_niter  = (const int*)d_in[2];
    const int* p_pad    = (const int*)d_in[3];
    const int* p_stride = (const int*)d_in[4];
    float* out = (float*)d_out;

    char* ws = (char*)d_ws;
    short*        Ghi   = (short*)ws;                     // 128 KB
    short*        Glo   = (short*)(ws + 131072);          // 128 KB
    double*       sxbuf = (double*)(ws + 262144);         // 2016 B (pad 4 KB)
    double*       gpart = (double*)(ws + 266240);         // 193536 B
    unsigned int* gcnt  = (unsigned int*)(ws + 266240 + 193536); // GCNT_N+1 u32

    hipMemsetAsync(gcnt, 0, (GCNT_N + 1) * sizeof(unsigned int), stream);
    window_kernel<<<dim3(GRID), dim3(512), 0, stream>>>(
        spec, basis, Ghi, Glo, p_niter, p_pad, p_stride, sxbuf, gpart, gcnt, out);
}

// Round 9
// 285.975 us; speedup vs baseline: 13.5938x; 1.3150x over previous
//
#include <hip/hip_runtime.h>
#include <math.h>

// SparseCoding, round 22.
// R21 post-mortem (334 us): VALUBusy 14% / MfmaUtil 3.8% both imply ~8.6K
// cycles/SIMD/iter -- 82% stall at 2 waves/SIMD. Itemized critical path
// explains ~half; the rest is inter-block machinery (agent-scope poll/atomic
// pairs, gbar rendezvous, 4-block skew) riding through every iteration.
// R22 ELIMINATES the transport: TWO KERNELS on the stream.
//  K1 (grid 256): Gram -> bf16 hi/lo planes (R20-proven) + per-quarter
//     stage/normalize/xB (bit-identical R13 chains); xB -> `out` used as
//     scratch in FINAL layout (K2 reads before any write; kernel boundary
//     orders K1 before K2 -- race-free); sx -> ws. No atomics.
//  K2 (grid 63, 1 block = 1 window): R19-proven LDS-local loop (parity ring,
//     lag-2 tid64 consume, post-loop round, Adam-undo epilogue) with:
//     - Gh RESIDENT in LDS for kk<7, tiled [kk][c][32] (112KB) -- bank-
//       balanced with NO swizzle (bank bits = {c&1, lh});
//     - kk=7 Gh + all Glo streamed from L2, static depth-2 rotation;
//     - SINGLE A buffer [kk][64][32] (32KB): writes post-barrier-B, reads
//       pre-barrier-B -> no double buffer needed; still 2 barriers/iter;
//     - zero atomics / spins / global transport of any kind.
// LDS K2 = 112K + 32K + ring ~ 147.6KB (1 blk/CU). VGPR demand ~118 < 128.
#define NB     256
#define NF     128
#define FT     1024
#define NW     63
#define TORIG  256
#define RPB    8

using f32x4  = __attribute__((ext_vector_type(4))) float;
using bf16x8 = __attribute__((ext_vector_type(8))) short;

// setup xB exchange layout (float4 index): k2*512 + row*64 + (cg ^ row)
__device__ __forceinline__ int xidx(int k2, int cg, int row) {
    return (k2 * 512 + row * 64 + (cg ^ row)) * 4;
}

// round-to-nearest-even fp32 -> bf16 bits (upper 16)
__device__ __forceinline__ unsigned bf16_hi(float x) {
    const unsigned u = __float_as_uint(x);
    return (u + 0x7fffu + ((u >> 16) & 1u)) >> 16;
}

// ======================= K1: Gram planes + window setup ======================
__global__ __launch_bounds__(512, 2) void setup_kernel(
    const float* __restrict__ spec,
    const float* __restrict__ basis,
    short* __restrict__ Ghi,             // ws: 256x256 bf16 hi plane
    short* __restrict__ Glo,             // ws: 256x256 bf16 lo plane
    const int* __restrict__ p_pad,
    const int* __restrict__ p_stride,
    double* __restrict__ sxw,            // ws: [NW][4]
    float* __restrict__ out)             // xB scratch (final layout)
{
    __shared__ __align__(16) float s_p0[RPB * 2048];   // 64 KB xB exchange
    __shared__ __align__(16) float s_xn[RPB * FT];     // 32 KB staging
    __shared__ float  s_gred[2][NB];
    __shared__ float  s_mn[RPB], s_rng[RPB];
    __shared__ double s_dred[8];

    const int bid = blockIdx.x;
    const int yy  = bid >> 3;
    const int q   = yy & 3;
    const int w   = (bid & 7) + 8 * (yy >> 2);
    const int tid = threadIdx.x;
    const int ks  = tid >> 6;
    const int kg  = tid & 63;
    const int r   = kg >> 3;
    const int cgo = 8 * ks + (kg & 7);

    // Gram: block bid computes G row bid -> hi/lo planes (R20-proven)
    {
        const int c = tid & 255, jh = tid >> 8;
        float acc = 0.f;
        const float* bp = basis + (size_t)(jh * 512) * NB;
        #pragma unroll 16
        for (int j = 0; j < 512; ++j)
            acc = fmaf(bp[j * NB + bid], bp[j * NB + c], acc);
        s_gred[jh][c] = acc;
        __syncthreads();
        if (jh == 0) {
            const float g = s_gred[0][c] + s_gred[1][c];
            const unsigned hb = bf16_hi(g);
            const float    hf = __uint_as_float(hb << 16);
            Ghi[(size_t)bid * NB + c] = (short)hb;
            Glo[(size_t)bid * NB + c] = (short)bf16_hi(g - hf);
        }
    }
    __syncthreads();
    if (w >= NW) return;

    const int t0 = w * p_stride[0] - p_pad[0];

    // stage rows q*8..q*8+8, min/max, normalize (R13 verbatim)
    #pragma unroll
    for (int i = 0; i < 16; ++i) {
        const int e = i * 512 + tid;
        const int b = e >> 10, jj = e & 1023;
        const int f = jj >> 3, t = jj & 7, tq = t0 + t;
        s_xn[b * FT + jj] = (tq >= 0 && tq < TORIG)
            ? spec[((size_t)(q * RPB + b) * NF + f) * TORIG + tq] : 0.f;
    }
    __syncthreads();
    {
        float mn = __builtin_inff(), mx = -__builtin_inff();
        #pragma unroll
        for (int i = 0; i < 16; ++i) {
            const float v = s_xn[ks * FT + i * 64 + kg];
            mn = fminf(mn, v); mx = fmaxf(mx, v);
        }
        #pragma unroll
        for (int off = 32; off; off >>= 1) {
            mn = fminf(mn, __shfl_down(mn, off));
            mx = fmaxf(mx, __shfl_down(mx, off));
        }
        if (kg == 0) { s_mn[ks] = mn; s_rng[ks] = mx - mn; }
    }
    __syncthreads();
    double sx2p = 0.0;
    #pragma unroll
    for (int i = 0; i < 16; ++i) {
        const int e = i * 512 + tid;
        const int b = e >> 10, jj = e & 1023;
        const float v = (s_xn[b * FT + jj] - s_mn[b]) / s_rng[b];
        s_xn[b * FT + jj] = v;
        sx2p += (double)v * (double)v;
    }
    #pragma unroll
    for (int off = 32; off; off >>= 1) sx2p += __shfl_down(sx2p, off);
    if (kg == 0) s_dred[ks] = sx2p;
    __syncthreads();
    if (tid == 0) {
        double s = 0.0;
        #pragma unroll
        for (int i = 0; i < 8; ++i) s += s_dred[i];
        sxw[w * 4 + q] = s;
    }

    // xB = xnorm @ basis (bit-identical R13 chains); write to out scratch
    float xbp[RPB][4];
    #pragma unroll
    for (int b = 0; b < RPB; ++b)
        #pragma unroll
        for (int j = 0; j < 4; ++j) xbp[b][j] = 0.f;
    for (int i0 = 0; i0 < 128; i0 += 4) {
        const int jj = ks * 128 + i0;
        float4 bv[4];
        #pragma unroll
        for (int t = 0; t < 4; ++t)
            bv[t] = *(const float4*)(basis + (size_t)(jj + t) * NB + 4 * kg);
        #pragma unroll
        for (int b = 0; b < RPB; ++b) {
            const float4 x4 = *(const float4*)&s_xn[b * FT + jj];
            xbp[b][0] = fmaf(x4.x, bv[0].x, fmaf(x4.y, bv[1].x, fmaf(x4.z, bv[2].x, fmaf(x4.w, bv[3].x, xbp[b][0]))));
            xbp[b][1] = fmaf(x4.x, bv[0].y, fmaf(x4.y, bv[1].y, fmaf(x4.z, bv[2].y, fmaf(x4.w, bv[3].y, xbp[b][1]))));
            xbp[b][2] = fmaf(x4.x, bv[0].z, fmaf(x4.y, bv[1].z, fmaf(x4.z, bv[2].z, fmaf(x4.w, bv[3].z, xbp[b][2]))));
            xbp[b][3] = fmaf(x4.x, bv[0].w, fmaf(x4.y, bv[1].w, fmaf(x4.z, bv[2].w, fmaf(x4.w, bv[3].w, xbp[b][3]))));
        }
    }
    __syncthreads();
    #pragma unroll
    for (int b = 0; b < RPB; ++b)
        *(float4*)&s_p0[xidx(ks, kg, b)] =
            make_float4(xbp[b][0], xbp[b][1], xbp[b][2], xbp[b][3]);
    __syncthreads();
    float xBo[4] = {0.f, 0.f, 0.f, 0.f};
    #pragma unroll
    for (int k2 = 0; k2 < 8; ++k2) {
        const float4 p4 = *(const float4*)&s_p0[xidx(k2, cgo, r)];
        xBo[0] += p4.x; xBo[1] += p4.y; xBo[2] += p4.z; xBo[3] += p4.w;
    }
    #pragma unroll
    for (int j = 0; j < 4; ++j)
        out[((size_t)(q * RPB + r) * NB + 4 * cgo + j) * NW + w] = xBo[j];
}

// ======================= K2: per-window Adam loop ============================
__global__ __launch_bounds__(512, 1) void loop_kernel(
    const short* __restrict__ Ghi,
    const short* __restrict__ Glo,
    const int* __restrict__ p_niter,
    const double* __restrict__ sxw,
    float* __restrict__ out)
{
    // arena: GhL [7][256][32] shorts (112KB) + Atile [8][64][32] shorts (32KB)
    __shared__ __align__(16) char arena[147456];
    char* const GhB = arena;                 // Gh LDS tiles, kk<7
    char* const Ab  = arena + 114688;        // single A buffer
    __shared__ float s_redq[2][8], s_redr[2][8];
    __shared__ int   s_stop[2];

    const int w   = blockIdx.x;
    const int tid = threadIdx.x;
    const int ks  = tid >> 6;                // wave 0..7: cols 32ks..32ks+32
    const int kg  = tid & 63;
    const int lr  = kg & 15;
    const int lh  = kg >> 4;
    const int c0  = 32 * ks + lr;
    const int n_iter = p_niter[0];

    // ---- owned xB from out-scratch (16 scattered dwords, one-time) ----
    float xB[16];
    #pragma unroll
    for (int pp = 0; pp < 2; ++pp)
        #pragma unroll
        for (int T = 0; T < 2; ++T)
            #pragma unroll
            for (int t = 0; t < 4; ++t)
                xB[pp * 8 + T * 4 + t] =
                    out[((size_t)(16 * pp + 4 * lh + t) * NB + 32 * ks + 16 * T + lr) * NW + w];

    // ---- Gh plane -> LDS tiles [kk][c][32], kk<7 (no swizzle needed) ----
    for (int g = tid; g < 7168; g += 512) {      // 16B granules
        const int kk = g >> 10, rem = g & 1023;
        const int c = rem >> 2, kch = rem & 3;
        *(float4*)(GhB + (size_t)g * 16) =
            *(const float4*)((const char*)Ghi + (size_t)(c * 32 + kk * 4 + kch) * 16);
    }

    // ---- init coef/Adam; fill A once (hi rows 0-31, lo rows 32-63) ----
    const float C0 = 0.5f / 256.f;
    float cf[16], m_[16], v_[16];
    #pragma unroll
    for (int j = 0; j < 16; ++j) { cf[j] = C0; m_[j] = 0.f; v_[j] = 0.f; }
    {
        const short vh = (short)bf16_hi(C0);     // C0 = 2^-9 exact, lo = 0
        #pragma unroll
        for (int pp = 0; pp < 2; ++pp)
            #pragma unroll
            for (int T = 0; T < 2; ++T)
                #pragma unroll
                for (int t = 0; t < 4; ++t) {
                    const int wbs = (ks * 2048 + (16 * pp + 4 * lh + t) * 32
                                     + 16 * T + lr) << 1;
                    *(short*)(Ab + wbs)        = vh;
                    *(short*)(Ab + wbs + 2048) = 0;      // +32 rows
                }
    }
    if (tid == 64) { s_stop[0] = 0; s_stop[1] = 0; }

    const short* glp = Glo + (size_t)c0 * NB + 8 * lh;   // +32*kk ; +4096 = T1
    const short* ghg = Ghi + (size_t)c0 * NB + 8 * lh;

    float b1p = 1.f, b2p = 1.f;
    float old_loss = 1e-10f;      // tid64 only
    double sxtot = 0.0;           // tid64 only
    const float c1c = 2.f / 32768.f, c2c = 0.2f / 8192.f;
    int use_prev = 0;

    for (int it = 0; it < n_iter; ++it) {
        const int p = it & 1;

        __syncthreads();          // barrier A: A writes (prev iter / init) visible

        // ---- MFMA: Gh from LDS (kk<7) / L2 (kk=7); Gl streamed depth-2 ----
        f32x4 acc00 = {0.f,0.f,0.f,0.f}, acc01 = {0.f,0.f,0.f,0.f};
        f32x4 acc10 = {0.f,0.f,0.f,0.f}, acc11 = {0.f,0.f,0.f,0.f};
        bf16x8 qa0, qb0, qa1, qb1;
        qa0 = *(const bf16x8*)(glp);
        qb0 = *(const bf16x8*)(glp + 4096);
        qa1 = *(const bf16x8*)(glp + 32);
        qb1 = *(const bf16x8*)(glp + 4096 + 32);
        const bf16x8 g7a = *(const bf16x8*)(ghg + 224);
        const bf16x8 g7b = *(const bf16x8*)(ghg + 4096 + 224);
        #pragma unroll
        for (int kk = 0; kk < 8; ++kk) {
            const bf16x8 Gl0 = (kk & 1) ? qa1 : qa0;
            const bf16x8 Gl1 = (kk & 1) ? qb1 : qb0;
            if (kk + 2 < 8) {
                if (kk & 1) {
                    qa1 = *(const bf16x8*)(glp + 32 * (kk + 2));
                    qb1 = *(const bf16x8*)(glp + 4096 + 32 * (kk + 2));
                } else {
                    qa0 = *(const bf16x8*)(glp + 32 * (kk + 2));
                    qb0 = *(const bf16x8*)(glp + 4096 + 32 * (kk + 2));
                }
            }
            bf16x8 Gh0, Gh1;
            if (kk < 7) {
                Gh0 = *(const bf16x8*)(GhB + ((kk * 8192 + c0 * 32 + 8 * lh) << 1));
                Gh1 = *(const bf16x8*)(GhB + ((kk * 8192 + (c0 + 16) * 32 + 8 * lh) << 1));
            } else { Gh0 = g7a; Gh1 = g7b; }
            const int ab = (kk * 2048 + lr * 32 + 8 * lh) << 1;
            const bf16x8 ah0 = *(const bf16x8*)(Ab + ab);
            const bf16x8 ah1 = *(const bf16x8*)(Ab + ab + 1024);   // rows 16-31
            const bf16x8 al0 = *(const bf16x8*)(Ab + ab + 2048);   // rows 32-47
            const bf16x8 al1 = *(const bf16x8*)(Ab + ab + 3072);   // rows 48-63
            acc00 = __builtin_amdgcn_mfma_f32_16x16x32_bf16(ah0, Gh0, acc00, 0, 0, 0);
            acc00 = __builtin_amdgcn_mfma_f32_16x16x32_bf16(al0, Gh0, acc00, 0, 0, 0);
            acc00 = __builtin_amdgcn_mfma_f32_16x16x32_bf16(ah0, Gl0, acc00, 0, 0, 0);
            acc10 = __builtin_amdgcn_mfma_f32_16x16x32_bf16(ah1, Gh0, acc10, 0, 0, 0);
            acc10 = __builtin_amdgcn_mfma_f32_16x16x32_bf16(al1, Gh0, acc10, 0, 0, 0);
            acc10 = __builtin_amdgcn_mfma_f32_16x16x32_bf16(ah1, Gl0, acc10, 0, 0, 0);
            acc01 = __builtin_amdgcn_mfma_f32_16x16x32_bf16(ah0, Gh1, acc01, 0, 0, 0);
            acc01 = __builtin_amdgcn_mfma_f32_16x16x32_bf16(al0, Gh1, acc01, 0, 0, 0);
            acc01 = __builtin_amdgcn_mfma_f32_16x16x32_bf16(ah0, Gl1, acc01, 0, 0, 0);
            acc11 = __builtin_amdgcn_mfma_f32_16x16x32_bf16(ah1, Gh1, acc11, 0, 0, 0);
            acc11 = __builtin_amdgcn_mfma_f32_16x16x32_bf16(al1, Gh1, acc11, 0, 0, 0);
            acc11 = __builtin_amdgcn_mfma_f32_16x16x32_bf16(ah1, Gl1, acc11, 0, 0, 0);
        }

        // ---- tid64: LAG-2 consume, entirely LDS-local (R19-proven) ----
        if (tid == 64 && it >= 2) {
            const int itc = it - 2;
            double Qt = 0.0, Rt = 0.0;
            #pragma unroll
            for (int i = 0; i < 8; ++i) {
                Qt += (double)s_redq[p][i];
                Rt += (double)s_redr[p][i];
            }
            if (itc == 0)
                sxtot = sxw[w*4+0] + sxw[w*4+1] + sxw[w*4+2] + sxw[w*4+3];
            const float loss = (float)((Qt + sxtot) / 32768.0 + 0.2 * (Rt / 8192.0));
            const float stat = fabsf(old_loss - loss) / old_loss;
            old_loss = loss;
            s_stop[p] = (stat < 1e-3f) ? 1 : 0;
        }

        __syncthreads();          // barrier B: A reads done + s_stop[p] visible

        if (s_stop[p]) { use_prev = 1; break; }

        // ---- fused loss-partial + Adam + A-write (cf read before update) ----
        b1p *= 0.9f; b2p *= 0.999f;
        const float rb1 = __builtin_amdgcn_rcpf(1.f - b1p);
        const float rb2 = __builtin_amdgcn_rcpf(1.f - b2p);
        float qc = 0.f, rr_ = 0.f;
        #pragma unroll
        for (int pp = 0; pp < 2; ++pp)
            #pragma unroll
            for (int T = 0; T < 2; ++T)
                #pragma unroll
                for (int t = 0; t < 4; ++t) {
                    const int j = pp * 8 + T * 4 + t;
                    const float a4v = (pp == 0) ? ((T == 0) ? acc00[t] : acc01[t])
                                                : ((T == 0) ? acc10[t] : acc11[t]);
                    const float xbj = xB[j];
                    const float c_  = cf[j];
                    qc  += c_ * (a4v - 2.f * xbj);
                    rr_ += fabsf(c_);
                    const float sgn = (c_ > 0.f) ? 1.f : ((c_ < 0.f) ? -1.f : 0.f);
                    const float gg  = c1c * (a4v - xbj) + c2c * sgn;
                    m_[j] = 0.9f * m_[j] + 0.1f * gg;
                    v_[j] = 0.999f * v_[j] + 0.001f * gg * gg;
                    const float den = __builtin_amdgcn_sqrtf(v_[j] * rb2) + 1e-8f;
                    cf[j] = c_ - 1e-3f * (m_[j] * rb1) * __builtin_amdgcn_rcpf(den);
                    const int wbs = (ks * 2048 + (16 * pp + 4 * lh + t) * 32
                                     + 16 * T + lr) << 1;
                    const unsigned hb = bf16_hi(cf[j]);
                    const float    hf = __uint_as_float(hb << 16);
                    *(short*)(Ab + wbs)        = (short)hb;
                    *(short*)(Ab + wbs + 2048) = (short)bf16_hi(cf[j] - hf);
                }
        if (it + 1 < n_iter) {
            #pragma unroll
            for (int off = 32; off; off >>= 1) {
                qc  += __shfl_down(qc, off);
                rr_ += __shfl_down(rr_, off);
            }
            if (kg == 0) { s_redq[p][ks] = qc; s_redr[p][ks] = rr_; }
        }
    }

    // ---- post-loop consume round: conv at t = n_iter-2 (if not stopped) ----
    if (!use_prev && n_iter >= 2) {
        if (tid == 64) {
            const int itc = n_iter - 2;
            const int pc  = itc & 1;
            double Qt = 0.0, Rt = 0.0;
            #pragma unroll
            for (int i = 0; i < 8; ++i) {
                Qt += (double)s_redq[pc][i];
                Rt += (double)s_redr[pc][i];
            }
            if (itc == 0)
                sxtot = sxw[w*4+0] + sxw[w*4+1] + sxw[w*4+2] + sxw[w*4+3];
            const float loss = (float)((Qt + sxtot) / 32768.0 + 0.2 * (Rt / 8192.0));
            const float stat = fabsf(old_loss - loss) / old_loss;
            s_stop[0] = (stat < 1e-3f) ? 1 : 0;
        }
        __syncthreads();
        use_prev = s_stop[0];
    }

    // ---- output; on stop reconstruct pre-step coef by exact Adam-step undo ----
    {
        const float rb1e = __builtin_amdgcn_rcpf(1.f - b1p);
        const float rb2e = __builtin_amdgcn_rcpf(1.f - b2p);
        #pragma unroll
        for (int pp = 0; pp < 2; ++pp)
            #pragma unroll
            for (int T = 0; T < 2; ++T)
                #pragma unroll
                for (int t = 0; t < 4; ++t) {
                    const int j = pp * 8 + T * 4 + t;
                    float val = cf[j];
                    if (use_prev) {
                        const float den = __builtin_amdgcn_sqrtf(v_[j] * rb2e) + 1e-8f;
                        val += 1e-3f * (m_[j] * rb1e) * __builtin_amdgcn_rcpf(den);
                    }
                    out[((size_t)(16 * pp + 4 * lh + t) * NB + 32 * ks + 16 * T + lr) * NW + w] = val;
                }
    }
}

// ---------------------------------------------------------------------------
extern "C" void kernel_launch(void* const* d_in, const int* in_sizes, int n_in,
                              void* d_out, int out_size, void* d_ws, size_t ws_size,
                              hipStream_t stream)
{
    const float* spec   = (const float*)d_in[0];
    const float* basis  = (const float*)d_in[1];
    const int* p_niter  = (const int*)d_in[2];
    const int* p_pad    = (const int*)d_in[3];
    const int* p_stride = (const int*)d_in[4];
    float* out = (float*)d_out;

    char* ws = (char*)d_ws;
    short*  Ghi = (short*)ws;                 // 128 KB
    short*  Glo = (short*)(ws + 131072);      // 128 KB
    double* sxw = (double*)(ws + 262144);     // 2016 B

    setup_kernel<<<dim3(256), dim3(512), 0, stream>>>(
        spec, basis, Ghi, Glo, p_pad, p_stride, sxw, out);
    loop_kernel<<<dim3(NW), dim3(512), 0, stream>>>(
        Ghi, Glo, p_niter, sxw, out);
}